// Round 9
// baseline (94.991 us; speedup 1.0000x reference)
//
#include <hip/hip_runtime.h>
#include <math.h>

typedef unsigned int u32;
typedef unsigned short ushort_t;
typedef __attribute__((ext_vector_type(8))) short short8;
typedef __attribute__((ext_vector_type(4))) float f32x4;
typedef __attribute__((ext_vector_type(16))) float f32x16;

#define B_G 16
#define S_MAX 512
#define NH 8
#define DH 32
#define HD 256
#define FFD 1024
#define ADJW 16            // u32 words per adjacency row (512 bits)

__device__ __forceinline__ ushort_t f2bf(float f) {
  u32 u = __float_as_uint(f);
  u += 0x7fffu + ((u >> 16) & 1u);
  return (ushort_t)(u >> 16);
}
__device__ __forceinline__ float bf2f(ushort_t s) {
  return __uint_as_float(((u32)s) << 16);
}

__device__ __forceinline__ void gll16(const void* g, void* l) {
  __builtin_amdgcn_global_load_lds(
      (const __attribute__((address_space(1))) unsigned int*)g,
      (__attribute__((address_space(3))) unsigned int*)l, 16, 0, 0);
}

// ---------- prep: zero adj | offsets+bias | weight cvt | h cvt (compact) ----------
__global__ __launch_bounds__(256) void k_prep2(u32* __restrict__ adj,
    const int* __restrict__ batch, int N, int* __restrict__ offs,
    const float* __restrict__ bq, const float* __restrict__ bk, float* __restrict__ bqk,
    const float* __restrict__ wa, const float* __restrict__ wb, const float* __restrict__ wc,
    const float* __restrict__ wd, const float* __restrict__ we,
    ushort_t* __restrict__ oa, ushort_t* __restrict__ ob, ushort_t* __restrict__ oc,
    ushort_t* __restrict__ od, ushort_t* __restrict__ oe,
    const float* __restrict__ h, ushort_t* __restrict__ hb) {
  int blk = blockIdx.x, tid = threadIdx.x;
  if (blk < 128) {
    uint4 z = {0u, 0u, 0u, 0u};
    ((uint4*)adj)[blk * 256 + tid] = z;
  } else if (blk == 128) {
    bqk[tid] = bq[tid];
    bqk[HD + tid] = bk[tid];
    if (tid <= B_G) {
      if (tid == B_G) { offs[B_G] = N; }
      else {
        int lo = 0, hi = N;
        while (lo < hi) { int mid = (lo + hi) >> 1; if (batch[mid] < tid) lo = mid + 1; else hi = mid; }
        offs[tid] = lo;
      }
    }
  } else if (blk < 481) {
    int bb = blk - 129;
    const float* src; ushort_t* dst; int off;
    if (bb < 32)       { src = wa; dst = oa; off = bb; }
    else if (bb < 64)  { src = wb; dst = ob; off = bb - 32; }
    else if (bb < 96)  { src = wc; dst = oc; off = bb - 64; }
    else if (bb < 224) { src = wd; dst = od; off = bb - 96; }
    else               { src = we; dst = oe; off = bb - 224; }
    size_t i = (size_t)off * 2048 + tid * 8;
    float4 v0 = *(const float4*)&src[i];
    float4 v1 = *(const float4*)&src[i + 4];
    uint4 pk;
    pk.x = (u32)f2bf(v0.x) | ((u32)f2bf(v0.y) << 16);
    pk.y = (u32)f2bf(v0.z) | ((u32)f2bf(v0.w) << 16);
    pk.z = (u32)f2bf(v1.x) | ((u32)f2bf(v1.y) << 16);
    pk.w = (u32)f2bf(v1.z) | ((u32)f2bf(v1.w) << 16);
    *(uint4*)&dst[i] = pk;
  } else {
    size_t i = ((size_t)(blk - 481) * 256 + tid) * 8;
    float4 v0 = *(const float4*)&h[i];
    float4 v1 = *(const float4*)&h[i + 4];
    uint4 pk;
    pk.x = (u32)f2bf(v0.x) | ((u32)f2bf(v0.y) << 16);
    pk.y = (u32)f2bf(v0.z) | ((u32)f2bf(v0.w) << 16);
    pk.z = (u32)f2bf(v1.x) | ((u32)f2bf(v1.y) << 16);
    pk.w = (u32)f2bf(v1.z) | ((u32)f2bf(v1.w) << 16);
    *(uint4*)&hb[i] = pk;
  }
}

// ---------- QK GEMM: 64x128 tile, BK=64, 256 thr, 2-phase; edge atomics folded ----------
__global__ __launch_bounds__(256) void k_qk(const ushort_t* __restrict__ A,
    const ushort_t* __restrict__ W, const float* __restrict__ bias,
    ushort_t* __restrict__ Cout, int gridx,
    const int* __restrict__ ei, int E, const int* __restrict__ batch,
    const int* __restrict__ offs, u32* __restrict__ adj) {
  __shared__ __align__(16) ushort_t As[2][64 * 64];
  __shared__ __align__(16) ushort_t Bs[2][128 * 64];
  int tid = threadIdx.x;
  int wid = tid >> 6, lane = tid & 63;
  int wm = wid & 1, wn = wid >> 1;
  int arow0 = blockIdx.x * 64, bcol0 = blockIdx.y * 128;

  {
    int e = (blockIdx.y * gridx + blockIdx.x) * 256 + tid;
    if (e < E) {
      int s = ei[e], d = ei[E + e];
      int b = batch[s];
      int o = offs[b];
      atomicOr(&adj[(b * S_MAX + (s - o)) * ADJW + ((d - o) >> 5)], 1u << ((d - o) & 31));
    }
  }

  const ushort_t* gA[2]; const ushort_t* gB[4];
  int dofsA[2], dofsB[4];
  #pragma unroll
  for (int i = 0; i < 2; i++) {
    int s = i * 256 + wid * 64 + lane;
    int r = s >> 3, ck = (s & 7) ^ (r & 7);
    gA[i] = A + (size_t)(arow0 + r) * HD + ck * 8;
    dofsA[i] = (i * 256 + wid * 64) * 8;
  }
  #pragma unroll
  for (int i = 0; i < 4; i++) {
    int s = i * 256 + wid * 64 + lane;
    int r = s >> 3, ck = (s & 7) ^ (r & 7);
    gB[i] = W + (size_t)(bcol0 + r) * HD + ck * 8;
    dofsB[i] = (i * 256 + wid * 64) * 8;
  }

  f32x4 acc[2][4];
  #pragma unroll
  for (int i = 0; i < 2; i++)
    #pragma unroll
    for (int j = 0; j < 4; j++) { f32x4 z = {0.f,0.f,0.f,0.f}; acc[i][j] = z; }

  #pragma unroll
  for (int i = 0; i < 2; i++) gll16(gA[i], &As[0][dofsA[i]]);
  #pragma unroll
  for (int i = 0; i < 4; i++) gll16(gB[i], &Bs[0][dofsB[i]]);
  asm volatile("s_waitcnt vmcnt(0)" ::: "memory");
  __builtin_amdgcn_s_barrier();

  int cur = 0;
  for (int ks = 0; ks < 4; ks++) {
    if (ks < 3) {
      int k0n = (ks + 1) << 6;
      #pragma unroll
      for (int i = 0; i < 2; i++) gll16(gA[i] + k0n, &As[cur ^ 1][dofsA[i]]);
      #pragma unroll
      for (int i = 0; i < 4; i++) gll16(gB[i] + k0n, &Bs[cur ^ 1][dofsB[i]]);
    }
    #pragma unroll
    for (int kk = 0; kk < 2; kk++) {
      short8 af[2], bfv[4];
      #pragma unroll
      for (int i = 0; i < 2; i++) {
        int row = wm * 32 + i * 16 + (lane & 15);
        int ck = (kk * 4 + (lane >> 4)) ^ (row & 7);
        af[i] = *(const short8*)&As[cur][row * 64 + ck * 8];
      }
      #pragma unroll
      for (int j = 0; j < 4; j++) {
        int row = wn * 64 + j * 16 + (lane & 15);
        int ck = (kk * 4 + (lane >> 4)) ^ (row & 7);
        bfv[j] = *(const short8*)&Bs[cur][row * 64 + ck * 8];
      }
      #pragma unroll
      for (int i = 0; i < 2; i++)
        #pragma unroll
        for (int j = 0; j < 4; j++)
          acc[i][j] = __builtin_amdgcn_mfma_f32_16x16x32_bf16(af[i], bfv[j], acc[i][j], 0, 0, 0);
    }
    asm volatile("s_waitcnt vmcnt(0)" ::: "memory");
    __builtin_amdgcn_s_barrier();
    cur ^= 1;
  }

  float bj[4]; int colb[4];
  #pragma unroll
  for (int j = 0; j < 4; j++) {
    colb[j] = bcol0 + wn * 64 + j * 16 + (lane & 15);
    bj[j] = bias[colb[j]];
  }
  #pragma unroll
  for (int i = 0; i < 2; i++) {
    #pragma unroll
    for (int r = 0; r < 4; r++) {
      int row = arow0 + wm * 32 + i * 16 + (lane >> 4) * 4 + r;
      #pragma unroll
      for (int j = 0; j < 4; j++)
        Cout[(size_t)row * 512 + colb[j]] = f2bf(acc[i][j][r] + bj[j]);
    }
  }
}

// ---------- fused masked attention, compact rows, analytic padding term ----------
__global__ __launch_bounds__(256) void k_attn(const ushort_t* __restrict__ qkb,
    const u32* __restrict__ adj, const int* __restrict__ offs,
    const float* __restrict__ bqk, ushort_t* __restrict__ attOb) {
  int bid = blockIdx.x;               // b(4b) | h(3b) | qtr(2b)
  int qtr = bid & 3, hh = (bid >> 2) & 7, b = bid >> 5;
  int nstart = offs[b], len = offs[b + 1] - nstart;
  int q0blk = qtr * 128;
  if (q0blk >= len) return;
  int lenT = len >> 5;

  __shared__ __align__(16) ushort_t K_lds[4 * 512 * 8];
  __shared__ __align__(16) ushort_t Kt_lds[64 * 32 * 8];
  __shared__ __align__(16) ushort_t P_lds[4 * 4 * 32 * 8];

  int tid = threadIdx.x;
  {
    const ushort_t* kg = qkb + (size_t)nstart * 512 + 256 + hh * 32;
    for (int t = tid; t < len; t += 256) {
      const uint4* src = (const uint4*)(kg + (size_t)t * 512);
      uint4 v0 = src[0], v1 = src[1], v2 = src[2], v3 = src[3];
      *(uint4*)&K_lds[0 * 4096 + t * 8] = v0;
      *(uint4*)&K_lds[1 * 4096 + t * 8] = v1;
      *(uint4*)&K_lds[2 * 4096 + t * 8] = v2;
      *(uint4*)&K_lds[3 * 4096 + t * 8] = v3;
    }
  }
  __syncthreads();
  {
    int d = tid & 31, tg = tid >> 5;
    int cc = d >> 3, e = d & 7;
    for (int i = 0; i < 8; i++) {
      int t0 = tg * 64 + i * 8;
      if (t0 < len) {
        u32 w0 = (u32)K_lds[cc * 4096 + (t0 + 0) * 8 + e] | ((u32)K_lds[cc * 4096 + (t0 + 1) * 8 + e] << 16);
        u32 w1 = (u32)K_lds[cc * 4096 + (t0 + 2) * 8 + e] | ((u32)K_lds[cc * 4096 + (t0 + 3) * 8 + e] << 16);
        u32 w2 = (u32)K_lds[cc * 4096 + (t0 + 4) * 8 + e] | ((u32)K_lds[cc * 4096 + (t0 + 5) * 8 + e] << 16);
        u32 w3 = (u32)K_lds[cc * 4096 + (t0 + 6) * 8 + e] | ((u32)K_lds[cc * 4096 + (t0 + 7) * 8 + e] << 16);
        uint4 pk = {w0, w1, w2, w3};
        *(uint4*)&Kt_lds[(t0 >> 3) * 256 + d * 8] = pk;
      }
    }
  }
  __syncthreads();

  int w = tid >> 6, lane = tid & 63;
  int q0w = q0blk + w * 32;
  if (q0w >= len) return;

  int lq = lane & 31, hf = lane >> 5;
  const float SCALE = 0.17677669529663687f;

  size_t qrow = (size_t)(nstart + q0w + lq) * 512 + hh * 32;
  short8 qf0 = *(const short8*)(qkb + qrow + hf * 8);
  short8 qf1 = *(const short8*)(qkb + qrow + 16 + hf * 8);

  const uint4* ap = (const uint4*)(adj + (size_t)(b * S_MAX + q0w + lq) * ADJW);
  uint4 a0 = ap[0], a1 = ap[1], a2 = ap[2], a3 = ap[3];
  u32 aw[16] = {a0.x, a0.y, a0.z, a0.w, a1.x, a1.y, a1.z, a1.w,
                a2.x, a2.y, a2.z, a2.w, a3.x, a3.y, a3.z, a3.w};

  f32x16 oacc = {0.f,0.f,0.f,0.f,0.f,0.f,0.f,0.f,0.f,0.f,0.f,0.f,0.f,0.f,0.f,0.f};
  float lsum = 0.f;

  for (int tt = 0; tt < lenT; tt++) {
    int t0 = tt * 32;
    short8 ka0 = *(const short8*)&K_lds[hf * 4096 + (t0 + lq) * 8];
    short8 ka1 = *(const short8*)&K_lds[(2 + hf) * 4096 + (t0 + lq) * 8];
    f32x16 sc = {0.f,0.f,0.f,0.f,0.f,0.f,0.f,0.f,0.f,0.f,0.f,0.f,0.f,0.f,0.f,0.f};
    sc = __builtin_amdgcn_mfma_f32_32x32x16_bf16(ka0, qf0, sc, 0, 0, 0);
    sc = __builtin_amdgcn_mfma_f32_32x32x16_bf16(ka1, qf1, sc, 0, 0, 0);
    u32 word = aw[tt];
    float p[16];
    #pragma unroll
    for (int r = 0; r < 16; r++) {
      int tb = (r & 3) + 8 * (r >> 2) + 4 * hf;
      float pe = __expf(sc[r] * SCALE);
      p[r] = ((word >> tb) & 1u) ? 0.f : pe;
      lsum += p[r];
    }
    #pragma unroll
    for (int g = 0; g < 4; g++) {
      u32 lo = (u32)f2bf(p[4 * g]) | ((u32)f2bf(p[4 * g + 1]) << 16);
      u32 hi = (u32)f2bf(p[4 * g + 2]) | ((u32)f2bf(p[4 * g + 3]) << 16);
      uint2 pk = {lo, hi};
      *(uint2*)&P_lds[w * 1024 + g * 256 + lq * 8 + hf * 4] = pk;
    }
    short8 va0 = *(const short8*)&Kt_lds[(t0 / 8 + hf) * 256 + lq * 8];
    short8 va1 = *(const short8*)&Kt_lds[(t0 / 8 + 2 + hf) * 256 + lq * 8];
    short8 pb0 = *(const short8*)&P_lds[w * 1024 + hf * 256 + lq * 8];
    short8 pb1 = *(const short8*)&P_lds[w * 1024 + (2 + hf) * 256 + lq * 8];
    oacc = __builtin_amdgcn_mfma_f32_32x32x16_bf16(va0, pb0, oacc, 0, 0, 0);
    oacc = __builtin_amdgcn_mfma_f32_32x32x16_bf16(va1, pb1, oacc, 0, 0, 0);
  }

  const float* bkh = bqk + 256 + hh * 32;
  float pq = 0.f;
  #pragma unroll
  for (int j = 0; j < 8; j++) pq += bf2f((ushort_t)qf0[j]) * bkh[hf * 8 + j];
  #pragma unroll
  for (int j = 0; j < 8; j++) pq += bf2f((ushort_t)qf1[j]) * bkh[16 + hf * 8 + j];
  pq += __shfl_xor(pq, 32, 64);
  float pe_pad = __expf(pq * SCALE) * (float)(S_MAX - len);

  float ltot = lsum + __shfl_xor(lsum, 32, 64) + pe_pad;
  float inv = 1.f / ltot;
  {
    int node = nstart + q0w + lq;
    ushort_t* op = attOb + (size_t)node * HD + hh * DH;
    #pragma unroll
    for (int g = 0; g < 4; g++) {
      float v0 = (oacc[4 * g]     + pe_pad * bkh[g * 8 + hf * 4 + 0]) * inv;
      float v1 = (oacc[4 * g + 1] + pe_pad * bkh[g * 8 + hf * 4 + 1]) * inv;
      float v2 = (oacc[4 * g + 2] + pe_pad * bkh[g * 8 + hf * 4 + 2]) * inv;
      float v3 = (oacc[4 * g + 3] + pe_pad * bkh[g * 8 + hf * 4 + 3]) * inv;
      u32 lo = (u32)f2bf(v0) | ((u32)f2bf(v1) << 16);
      u32 hi = (u32)f2bf(v2) | ((u32)f2bf(v3) << 16);
      uint2 pk = {lo, hi};
      *(uint2*)(op + g * 8 + hf * 4) = pk;
    }
  }
}

// ---------- fused tail: out-proj + LN1 + FFN-up + FFN-down + LN2 ----------
// 200 blocks x 32 rows x 256 thr. Single 36-step B-tile stream (4 Wo; per FF
// chunk c: 2 W1 halves + 2 W2 quarters), tri-buffered LDS, counted vmcnt(16)
// depth-3 pipeline (uniform 8 gll16/stage; in-order retirement). Epilogues use
// lgkmcnt(0)+raw s_barrier so they never drain VMEM. h1 lives in registers;
// h1b and ff1-chunks live in LDS only.
__global__ __launch_bounds__(256) void k_tail(
    const ushort_t* __restrict__ attOb, const ushort_t* __restrict__ Wob,
    const float* __restrict__ bo, const float* __restrict__ hres,
    const float* __restrict__ g1, const float* __restrict__ be1,
    const ushort_t* __restrict__ W1b, const float* __restrict__ b1,
    const ushort_t* __restrict__ W2b, const float* __restrict__ b2,
    const float* __restrict__ g2, const float* __restrict__ be2,
    float* __restrict__ outF) {
  __shared__ __align__(16) ushort_t Ah[32 * 256];      // 16KB: attO, then h1b
  __shared__ __align__(16) ushort_t Bst[3][16384];     // 96KB tri-buffer
  __shared__ __align__(16) ushort_t Fc[32 * 128];      // 8KB ff1 chunk (bf16)
  __shared__ __align__(16) float bv[2560];             // 10KB: bo|g1|be1|b2|g2|be2|b1
  __shared__ float red_s[128], red_q[128];
  int tid = threadIdx.x, wid = tid >> 6, lane = tid & 63, wn = wid;
  int row0 = blockIdx.x * 32;

  // bias vectors -> LDS (issued first; retire earliest)
  #pragma unroll
  for (int i = 0; i < 3; i++) {
    int u = i * 256 + tid;
    if (u < 640) {
      int o = u * 4;
      const float* src;
      if      (o < 256)  src = bo  + o;
      else if (o < 512)  src = g1  + (o - 256);
      else if (o < 768)  src = be1 + (o - 512);
      else if (o < 1024) src = b2  + (o - 768);
      else if (o < 1280) src = g2  + (o - 1024);
      else if (o < 1536) src = be2 + (o - 1280);
      else               src = b1  + (o - 1536);
      gll16(src, &bv[(i * 256 + wid * 64) * 4]);
    }
  }
  // residual rows -> regs
  float hr[2][4][4];
  #pragma unroll
  for (int m = 0; m < 2; m++)
    #pragma unroll
    for (int rr = 0; rr < 4; rr++) {
      int row_l = m * 16 + (lane >> 4) * 4 + rr;
      #pragma unroll
      for (int n = 0; n < 4; n++)
        hr[m][n][rr] = hres[(size_t)(row0 + row_l) * HD + wn * 64 + n * 16 + (lane & 15)];
    }
  // attO rows -> Ah (chunk-swizzled)
  #pragma unroll
  for (int i = 0; i < 4; i++) {
    int s = i * 256 + tid;
    int r = s >> 5, ck = s & 31;
    gll16(attOb + (size_t)(row0 + r) * HD + ((ck ^ (r & 7)) * 8),
          &Ah[(i * 256 + wid * 64) * 8]);
  }

  auto STAGE = [&](int t, int buf) {
    ushort_t* dst0 = &Bst[buf][0];
    if (t < 4) {                       // Wo k-step t: 256 rows x 64k
      #pragma unroll
      for (int i = 0; i < 8; i++) {
        int s = i * 256 + tid;
        int r = s >> 3, ck = s & 7;
        gll16(Wob + (size_t)r * HD + t * 64 + ((ck ^ (r & 7)) * 8),
              dst0 + (i * 256 + wid * 64) * 8);
      }
    } else {
      int u = t - 4, c = u >> 2, p = u & 3;
      if (p < 2) {                     // W1 chunk c, K-half p: 128 rows x 128k
        #pragma unroll
        for (int i = 0; i < 8; i++) {
          int s = i * 256 + tid;
          int r = s >> 4, ck = s & 15;
          gll16(W1b + (size_t)(c * 128 + r) * HD + p * 128 + ((ck ^ (r & 7)) * 8),
                dst0 + (i * 256 + wid * 64) * 8);
        }
      } else {                         // W2, k-slice c*128+(p-2)*64: 256 rows x 64k
        #pragma unroll
        for (int i = 0; i < 8; i++) {
          int s = i * 256 + tid;
          int r = s >> 3, ck = s & 7;
          gll16(W2b + (size_t)r * FFD + c * 128 + (p - 2) * 64 + ((ck ^ (r & 7)) * 8),
                dst0 + (i * 256 + wid * 64) * 8);
        }
      }
    }
  };

  f32x4 acc[2][4], ff2[2][4], acc1[2][2], hreg[2][4];
  #pragma unroll
  for (int m = 0; m < 2; m++)
    #pragma unroll
    for (int n = 0; n < 4; n++) { f32x4 z = {0.f,0.f,0.f,0.f}; acc[m][n] = z; ff2[m][n] = z; }

  STAGE(0, 0); STAGE(1, 1); STAGE(2, 2);

  for (int t = 0; t < 36; t++) {
    if (t < 34) { asm volatile("s_waitcnt vmcnt(16)" ::: "memory"); }
    else        { asm volatile("s_waitcnt vmcnt(0)" ::: "memory"); }
    __builtin_amdgcn_s_barrier();
    int buf = t % 3;
    if (t < 4) {
      // out-proj step
      #pragma unroll
      for (int kk = 0; kk < 2; kk++) {
        short8 af[2], bfv[4];
        #pragma unroll
        for (int m = 0; m < 2; m++) {
          int r = m * 16 + (lane & 15);
          int pos = (t * 8 + kk * 4 + (lane >> 4)) ^ (r & 7);
          af[m] = *(const short8*)&Ah[r * 256 + pos * 8];
        }
        #pragma unroll
        for (int n = 0; n < 4; n++) {
          int rB = wn * 64 + n * 16 + (lane & 15);
          int pos = (kk * 4 + (lane >> 4)) ^ (rB & 7);
          bfv[n] = *(const short8*)&Bst[buf][rB * 64 + pos * 8];
        }
        #pragma unroll
        for (int m = 0; m < 2; m++)
          #pragma unroll
          for (int n = 0; n < 4; n++)
            acc[m][n] = __builtin_amdgcn_mfma_f32_16x16x32_bf16(af[m], bfv[n], acc[m][n], 0, 0, 0);
      }
    } else {
      int u = t - 4, c = u >> 2, p = u & 3;
      if (p < 2) {
        // FFN-up half (K=128)
        if (p == 0) {
          #pragma unroll
          for (int m = 0; m < 2; m++)
            #pragma unroll
            for (int n = 0; n < 2; n++) { f32x4 z = {0.f,0.f,0.f,0.f}; acc1[m][n] = z; }
        }
        #pragma unroll
        for (int kk = 0; kk < 4; kk++) {
          short8 af[2], bfv[2];
          #pragma unroll
          for (int m = 0; m < 2; m++) {
            int r = m * 16 + (lane & 15);
            int pos = (p * 16 + kk * 4 + (lane >> 4)) ^ (r & 7);
            af[m] = *(const short8*)&Ah[r * 256 + pos * 8];
          }
          #pragma unroll
          for (int n = 0; n < 2; n++) {
            int rB = wn * 32 + n * 16 + (lane & 15);
            int pos = (kk * 4 + (lane >> 4)) ^ (rB & 7);
            bfv[n] = *(const short8*)&Bst[buf][rB * 128 + pos * 8];
          }
          #pragma unroll
          for (int m = 0; m < 2; m++)
            #pragma unroll
            for (int n = 0; n < 2; n++)
              acc1[m][n] = __builtin_amdgcn_mfma_f32_16x16x32_bf16(af[m], bfv[n], acc1[m][n], 0, 0, 0);
        }
      } else {
        // FFN-down quarter (K=64)
        #pragma unroll
        for (int kk = 0; kk < 2; kk++) {
          short8 af[2], bfv[4];
          #pragma unroll
          for (int m = 0; m < 2; m++) {
            int r = m * 16 + (lane & 15);
            int pos = ((p - 2) * 8 + kk * 4 + (lane >> 4)) ^ (r & 7);
            af[m] = *(const short8*)&Fc[r * 128 + pos * 8];
          }
          #pragma unroll
          for (int n = 0; n < 4; n++) {
            int rB = wn * 64 + n * 16 + (lane & 15);
            int pos = (kk * 4 + (lane >> 4)) ^ (rB & 7);
            bfv[n] = *(const short8*)&Bst[buf][rB * 64 + pos * 8];
          }
          #pragma unroll
          for (int m = 0; m < 2; m++)
            #pragma unroll
            for (int n = 0; n < 4; n++)
              ff2[m][n] = __builtin_amdgcn_mfma_f32_16x16x32_bf16(af[m], bfv[n], ff2[m][n], 0, 0, 0);
        }
      }
    }
    // ---- epilogues ----
    if (t == 3) {
      // LN1: bias + residual + stats; h1 -> hreg, h1b -> Ah
      #pragma unroll
      for (int m = 0; m < 2; m++)
        #pragma unroll
        for (int rr = 0; rr < 4; rr++) {
          int row_l = m * 16 + (lane >> 4) * 4 + rr;
          float s = 0.f, q = 0.f;
          #pragma unroll
          for (int n = 0; n < 4; n++) {
            int col = wn * 64 + n * 16 + (lane & 15);
            float v = acc[m][n][rr] + bv[col] + hr[m][n][rr];
            acc[m][n][rr] = v;
            s += v; q += v * v;
          }
          #pragma unroll
          for (int o = 1; o < 16; o <<= 1) { s += __shfl_xor(s, o, 64); q += __shfl_xor(q, o, 64); }
          if ((lane & 15) == 0) { red_s[row_l * 4 + wn] = s; red_q[row_l * 4 + wn] = q; }
        }
      asm volatile("s_waitcnt lgkmcnt(0)" ::: "memory");
      __builtin_amdgcn_s_barrier();          // also guards Ah overwrite below
      #pragma unroll
      for (int m = 0; m < 2; m++)
        #pragma unroll
        for (int rr = 0; rr < 4; rr++) {
          int row_l = m * 16 + (lane >> 4) * 4 + rr;
          float ssum = red_s[row_l * 4] + red_s[row_l * 4 + 1] + red_s[row_l * 4 + 2] + red_s[row_l * 4 + 3];
          float qsum = red_q[row_l * 4] + red_q[row_l * 4 + 1] + red_q[row_l * 4 + 2] + red_q[row_l * 4 + 3];
          float mu = ssum * (1.f / HD);
          float var = qsum * (1.f / HD) - mu * mu;
          float inv = rsqrtf(var + 1e-5f);
          #pragma unroll
          for (int n = 0; n < 4; n++) {
            int col = wn * 64 + n * 16 + (lane & 15);
            float v = (acc[m][n][rr] - mu) * inv * bv[256 + col] + bv[512 + col];
            hreg[m][n][rr] = v;
            int pos = ((col >> 3) ^ (row_l & 7));
            Ah[row_l * 256 + pos * 8 + (col & 7)] = f2bf(v);
          }
        }
      asm volatile("s_waitcnt lgkmcnt(0)" ::: "memory");
    } else if (t >= 4 && ((t - 4) & 3) == 1) {
      // ff1 chunk done: bias + relu + pack to Fc
      int c = (t - 4) >> 2;
      #pragma unroll
      for (int m = 0; m < 2; m++)
        #pragma unroll
        for (int rr = 0; rr < 4; rr++) {
          int row_l = m * 16 + (lane >> 4) * 4 + rr;
          #pragma unroll
          for (int n = 0; n < 2; n++) {
            int col = wn * 32 + n * 16 + (lane & 15);
            float v = fmaxf(acc1[m][n][rr] + bv[1536 + c * 128 + col], 0.f);
            int pos = ((col >> 3) ^ (row_l & 7));
            Fc[row_l * 128 + pos * 8 + (col & 7)] = f2bf(v);
          }
        }
      asm volatile("s_waitcnt lgkmcnt(0)" ::: "memory");
    }
    __builtin_amdgcn_s_barrier();
    if (t + 3 < 36) STAGE(t + 3, (t + 3) % 3);
  }

  // LN2 epilogue -> out
  #pragma unroll
  for (int m = 0; m < 2; m++)
    #pragma unroll
    for (int rr = 0; rr < 4; rr++) {
      int row_l = m * 16 + (lane >> 4) * 4 + rr;
      float s = 0.f, q = 0.f;
      #pragma unroll
      for (int n = 0; n < 4; n++) {
        int col = wn * 64 + n * 16 + (lane & 15);
        float v = ff2[m][n][rr] + bv[768 + col] + hreg[m][n][rr];
        ff2[m][n][rr] = v;
        s += v; q += v * v;
      }
      #pragma unroll
      for (int o = 1; o < 16; o <<= 1) { s += __shfl_xor(s, o, 64); q += __shfl_xor(q, o, 64); }
      if ((lane & 15) == 0) { red_s[row_l * 4 + wn] = s; red_q[row_l * 4 + wn] = q; }
    }
  asm volatile("s_waitcnt lgkmcnt(0)" ::: "memory");
  __builtin_amdgcn_s_barrier();
  #pragma unroll
  for (int m = 0; m < 2; m++)
    #pragma unroll
    for (int rr = 0; rr < 4; rr++) {
      int row_l = m * 16 + (lane >> 4) * 4 + rr;
      float ssum = red_s[row_l * 4] + red_s[row_l * 4 + 1] + red_s[row_l * 4 + 2] + red_s[row_l * 4 + 3];
      float qsum = red_q[row_l * 4] + red_q[row_l * 4 + 1] + red_q[row_l * 4 + 2] + red_q[row_l * 4 + 3];
      float mu = ssum * (1.f / HD);
      float var = qsum * (1.f / HD) - mu * mu;
      float inv = rsqrtf(var + 1e-5f);
      size_t rb = (size_t)(row0 + row_l) * HD;
      #pragma unroll
      for (int n = 0; n < 4; n++) {
        int col = wn * 64 + n * 16 + (lane & 15);
        outF[rb + col] = (ff2[m][n][rr] - mu) * inv * bv[1024 + col] + bv[1280 + col];
      }
    }
}

extern "C" void kernel_launch(void* const* d_in, const int* in_sizes, int n_in,
                              void* d_out, int out_size, void* d_ws, size_t ws_size,
                              hipStream_t stream) {
  const float* h   = (const float*)d_in[0];
  const float* Wq  = (const float*)d_in[1];
  const float* bq  = (const float*)d_in[2];
  const float* Wk  = (const float*)d_in[3];
  const float* bk  = (const float*)d_in[4];
  // d_in[5], d_in[6] (Wv, bv) unused: reference V uses the K projection
  const float* Wo  = (const float*)d_in[7];
  const float* bo  = (const float*)d_in[8];
  const float* W1  = (const float*)d_in[9];
  const float* b1  = (const float*)d_in[10];
  const float* W2  = (const float*)d_in[11];
  const float* b2  = (const float*)d_in[12];
  const float* g1  = (const float*)d_in[13];
  const float* be1 = (const float*)d_in[14];
  const float* g2  = (const float*)d_in[15];
  const float* be2 = (const float*)d_in[16];
  const int* batch = (const int*)d_in[17];
  const int* ei    = (const int*)d_in[18];
  int N = in_sizes[0] / HD;       // 6400
  int E = in_sizes[18] / 2;       // 102400

  char* ws = (char*)d_ws;
  ushort_t* hb    = (ushort_t*)(ws);                        // 3.2MB [6400,256] bf16 (later attO)
  ushort_t* attOb = hb;
  ushort_t* qkb   = (ushort_t*)(ws + ((size_t)4 << 20));    // 6.4MB [6400,512] bf16
  char* wbase = ws + ((size_t)36 << 20);
  ushort_t* Wqkb = (ushort_t*)(wbase);                      // 256KB [512,256]
  ushort_t* Wob  = (ushort_t*)(wbase + (256 << 10));        // 128KB
  ushort_t* W1b  = (ushort_t*)(wbase + (384 << 10));        // 512KB [1024,256]
  ushort_t* W2b  = (ushort_t*)(wbase + (896 << 10));        // 512KB [256,1024]
  float*    bqk  = (float*)(wbase + (1408 << 10));          // 2KB  [512]
  u32*      adj  = (u32*)(wbase + (1536 << 10));            // 512KB
  int*      offs = (int*)(ws + ((size_t)38 << 20));         // 128B

  // P1: adj zero | offsets+bias | weight cvt | compact h cvt
  k_prep2<<<1281, 256, 0, stream>>>(adj, batch, N, offs, bq, bk, bqk,
                                    Wq, Wk, Wo, W1, W2,
                                    Wqkb, Wqkb + 65536, Wob, W1b, W2b, h, hb);
  // P2: fused Q|K projection + edge atomics
  k_qk<<<dim3(100, 4), 256, 0, stream>>>(hb, Wqkb, bqk, qkb, 100,
                                         ei, E, batch, offs, adj);
  // P3: attention (compact, analytic padding) -> attOb
  k_attn<<<B_G * NH * 4, 256, 0, stream>>>(qkb, adj, offs, bqk, attOb);
  // P4: fused out-proj + LN1 + FFN + LN2 -> d_out
  k_tail<<<200, 256, 0, stream>>>(attOb, Wob, bo, h, g1, be1,
                                  W1b, b1, W2b, b2, g2, be2, (float*)d_out);
}

// Round 10
// 86.660 us; speedup vs baseline: 1.0961x; 1.0961x over previous
//
#include <hip/hip_runtime.h>
#include <math.h>

typedef unsigned int u32;
typedef unsigned short ushort_t;
typedef __attribute__((ext_vector_type(8))) short short8;
typedef __attribute__((ext_vector_type(4))) float f32x4;
typedef __attribute__((ext_vector_type(16))) float f32x16;

#define B_G 16
#define S_MAX 512
#define NH 8
#define DH 32
#define HD 256
#define FFD 1024
#define ADJW 16            // u32 words per adjacency row (512 bits)

__device__ __forceinline__ ushort_t f2bf(float f) {
  u32 u = __float_as_uint(f);
  u += 0x7fffu + ((u >> 16) & 1u);
  return (ushort_t)(u >> 16);
}
__device__ __forceinline__ float bf2f(ushort_t s) {
  return __uint_as_float(((u32)s) << 16);
}

__device__ __forceinline__ void gll16(const void* g, void* l) {
  __builtin_amdgcn_global_load_lds(
      (const __attribute__((address_space(1))) unsigned int*)g,
      (__attribute__((address_space(3))) unsigned int*)l, 16, 0, 0);
}

// ---------- prep: zero adj | offsets+bias | weight cvt | h cvt (compact) ----------
__global__ __launch_bounds__(256) void k_prep2(u32* __restrict__ adj,
    const int* __restrict__ batch, int N, int* __restrict__ offs,
    const float* __restrict__ bq, const float* __restrict__ bk, float* __restrict__ bqk,
    const float* __restrict__ wa, const float* __restrict__ wb, const float* __restrict__ wc,
    const float* __restrict__ wd, const float* __restrict__ we,
    ushort_t* __restrict__ oa, ushort_t* __restrict__ ob, ushort_t* __restrict__ oc,
    ushort_t* __restrict__ od, ushort_t* __restrict__ oe,
    const float* __restrict__ h, ushort_t* __restrict__ hb) {
  int blk = blockIdx.x, tid = threadIdx.x;
  if (blk < 128) {
    uint4 z = {0u, 0u, 0u, 0u};
    ((uint4*)adj)[blk * 256 + tid] = z;
  } else if (blk == 128) {
    bqk[tid] = bq[tid];
    bqk[HD + tid] = bk[tid];
    if (tid <= B_G) {
      if (tid == B_G) { offs[B_G] = N; }
      else {
        int lo = 0, hi = N;
        while (lo < hi) { int mid = (lo + hi) >> 1; if (batch[mid] < tid) lo = mid + 1; else hi = mid; }
        offs[tid] = lo;
      }
    }
  } else if (blk < 481) {
    int bb = blk - 129;
    const float* src; ushort_t* dst; int off;
    if (bb < 32)       { src = wa; dst = oa; off = bb; }
    else if (bb < 64)  { src = wb; dst = ob; off = bb - 32; }
    else if (bb < 96)  { src = wc; dst = oc; off = bb - 64; }
    else if (bb < 224) { src = wd; dst = od; off = bb - 96; }
    else               { src = we; dst = oe; off = bb - 224; }
    size_t i = (size_t)off * 2048 + tid * 8;
    float4 v0 = *(const float4*)&src[i];
    float4 v1 = *(const float4*)&src[i + 4];
    uint4 pk;
    pk.x = (u32)f2bf(v0.x) | ((u32)f2bf(v0.y) << 16);
    pk.y = (u32)f2bf(v0.z) | ((u32)f2bf(v0.w) << 16);
    pk.z = (u32)f2bf(v1.x) | ((u32)f2bf(v1.y) << 16);
    pk.w = (u32)f2bf(v1.z) | ((u32)f2bf(v1.w) << 16);
    *(uint4*)&dst[i] = pk;
  } else {
    size_t i = ((size_t)(blk - 481) * 256 + tid) * 8;
    float4 v0 = *(const float4*)&h[i];
    float4 v1 = *(const float4*)&h[i + 4];
    uint4 pk;
    pk.x = (u32)f2bf(v0.x) | ((u32)f2bf(v0.y) << 16);
    pk.y = (u32)f2bf(v0.z) | ((u32)f2bf(v0.w) << 16);
    pk.z = (u32)f2bf(v1.x) | ((u32)f2bf(v1.y) << 16);
    pk.w = (u32)f2bf(v1.z) | ((u32)f2bf(v1.w) << 16);
    *(uint4*)&hb[i] = pk;
  }
}

// ---------- QK GEMM: 64x128 tile, BK=64, 256 thr; counted-vmcnt pipeline ----------
// Per step: issue next stage (6 gll16) -> s_waitcnt vmcnt(6) (waits ONLY the
// previous stage; own-wave counter, barrier publishes) -> barrier -> MFMA ->
// barrier. Next-stage loads stay in flight across compute (T4). Prologue
// vmcnt(0) also fences the edge-atomic vmem ops so counting stays exact.
__global__ __launch_bounds__(256) void k_qk(const ushort_t* __restrict__ A,
    const ushort_t* __restrict__ W, const float* __restrict__ bias,
    ushort_t* __restrict__ Cout, int gridx,
    const int* __restrict__ ei, int E, const int* __restrict__ batch,
    const int* __restrict__ offs, u32* __restrict__ adj) {
  __shared__ __align__(16) ushort_t As[2][64 * 64];
  __shared__ __align__(16) ushort_t Bs[2][128 * 64];
  int tid = threadIdx.x;
  int wid = tid >> 6, lane = tid & 63;
  int wm = wid & 1, wn = wid >> 1;
  int arow0 = blockIdx.x * 64, bcol0 = blockIdx.y * 128;

  {
    int e = (blockIdx.y * gridx + blockIdx.x) * 256 + tid;
    if (e < E) {
      int s = ei[e], d = ei[E + e];
      int b = batch[s];
      int o = offs[b];
      atomicOr(&adj[(b * S_MAX + (s - o)) * ADJW + ((d - o) >> 5)], 1u << ((d - o) & 31));
    }
  }

  const ushort_t* gA[2]; const ushort_t* gB[4];
  int dofsA[2], dofsB[4];
  #pragma unroll
  for (int i = 0; i < 2; i++) {
    int s = i * 256 + wid * 64 + lane;
    int r = s >> 3, ck = (s & 7) ^ (r & 7);
    gA[i] = A + (size_t)(arow0 + r) * HD + ck * 8;
    dofsA[i] = (i * 256 + wid * 64) * 8;
  }
  #pragma unroll
  for (int i = 0; i < 4; i++) {
    int s = i * 256 + wid * 64 + lane;
    int r = s >> 3, ck = (s & 7) ^ (r & 7);
    gB[i] = W + (size_t)(bcol0 + r) * HD + ck * 8;
    dofsB[i] = (i * 256 + wid * 64) * 8;
  }

  f32x4 acc[2][4];
  #pragma unroll
  for (int i = 0; i < 2; i++)
    #pragma unroll
    for (int j = 0; j < 4; j++) { f32x4 z = {0.f,0.f,0.f,0.f}; acc[i][j] = z; }

  #pragma unroll
  for (int i = 0; i < 2; i++) gll16(gA[i], &As[0][dofsA[i]]);
  #pragma unroll
  for (int i = 0; i < 4; i++) gll16(gB[i], &Bs[0][dofsB[i]]);
  asm volatile("s_waitcnt vmcnt(0)" ::: "memory");
  __builtin_amdgcn_s_barrier();

  int cur = 0;
  for (int ks = 0; ks < 4; ks++) {
    if (ks < 3) {
      int k0n = (ks + 1) << 6;
      #pragma unroll
      for (int i = 0; i < 2; i++) gll16(gA[i] + k0n, &As[cur ^ 1][dofsA[i]]);
      #pragma unroll
      for (int i = 0; i < 4; i++) gll16(gB[i] + k0n, &Bs[cur ^ 1][dofsB[i]]);
      asm volatile("s_waitcnt vmcnt(6)" ::: "memory");
    } else {
      asm volatile("s_waitcnt vmcnt(0)" ::: "memory");
    }
    __builtin_amdgcn_s_barrier();
    #pragma unroll
    for (int kk = 0; kk < 2; kk++) {
      short8 af[2], bfv[4];
      #pragma unroll
      for (int i = 0; i < 2; i++) {
        int row = wm * 32 + i * 16 + (lane & 15);
        int ck = (kk * 4 + (lane >> 4)) ^ (row & 7);
        af[i] = *(const short8*)&As[cur][row * 64 + ck * 8];
      }
      #pragma unroll
      for (int j = 0; j < 4; j++) {
        int row = wn * 64 + j * 16 + (lane & 15);
        int ck = (kk * 4 + (lane >> 4)) ^ (row & 7);
        bfv[j] = *(const short8*)&Bs[cur][row * 64 + ck * 8];
      }
      #pragma unroll
      for (int i = 0; i < 2; i++)
        #pragma unroll
        for (int j = 0; j < 4; j++)
          acc[i][j] = __builtin_amdgcn_mfma_f32_16x16x32_bf16(af[i], bfv[j], acc[i][j], 0, 0, 0);
    }
    __builtin_amdgcn_s_barrier();
    cur ^= 1;
  }

  float bj[4]; int colb[4];
  #pragma unroll
  for (int j = 0; j < 4; j++) {
    colb[j] = bcol0 + wn * 64 + j * 16 + (lane & 15);
    bj[j] = bias[colb[j]];
  }
  #pragma unroll
  for (int i = 0; i < 2; i++) {
    #pragma unroll
    for (int r = 0; r < 4; r++) {
      int row = arow0 + wm * 32 + i * 16 + (lane >> 4) * 4 + r;
      #pragma unroll
      for (int j = 0; j < 4; j++)
        Cout[(size_t)row * 512 + colb[j]] = f2bf(acc[i][j][r] + bj[j]);
    }
  }
}

// ---------- FFN-up GEMM: 64x128 tile, BK=64, relu, bf16 out; counted vmcnt ----------
__global__ __launch_bounds__(256) void k_ffup(const ushort_t* __restrict__ A,
    const ushort_t* __restrict__ W, const float* __restrict__ bias,
    ushort_t* __restrict__ Cout, int Ncols, int Kdim) {
  __shared__ __align__(16) ushort_t As[2][64 * 64];
  __shared__ __align__(16) ushort_t Bs[2][128 * 64];
  int tid = threadIdx.x;
  int wid = tid >> 6, lane = tid & 63;
  int wm = wid & 1, wn = wid >> 1;
  int arow0 = blockIdx.x * 64, bcol0 = blockIdx.y * 128;

  const ushort_t* gA[2]; const ushort_t* gB[4];
  int dofsA[2], dofsB[4];
  #pragma unroll
  for (int i = 0; i < 2; i++) {
    int s = i * 256 + wid * 64 + lane;
    int r = s >> 3, ck = (s & 7) ^ (r & 7);
    gA[i] = A + (size_t)(arow0 + r) * Kdim + ck * 8;
    dofsA[i] = (i * 256 + wid * 64) * 8;
  }
  #pragma unroll
  for (int i = 0; i < 4; i++) {
    int s = i * 256 + wid * 64 + lane;
    int r = s >> 3, ck = (s & 7) ^ (r & 7);
    gB[i] = W + (size_t)(bcol0 + r) * Kdim + ck * 8;
    dofsB[i] = (i * 256 + wid * 64) * 8;
  }

  f32x4 acc[2][4];
  #pragma unroll
  for (int i = 0; i < 2; i++)
    #pragma unroll
    for (int j = 0; j < 4; j++) { f32x4 z = {0.f,0.f,0.f,0.f}; acc[i][j] = z; }

  #pragma unroll
  for (int i = 0; i < 2; i++) gll16(gA[i], &As[0][dofsA[i]]);
  #pragma unroll
  for (int i = 0; i < 4; i++) gll16(gB[i], &Bs[0][dofsB[i]]);
  asm volatile("s_waitcnt vmcnt(0)" ::: "memory");
  __builtin_amdgcn_s_barrier();

  int nsteps = Kdim >> 6;
  int cur = 0;
  for (int ks = 0; ks < nsteps; ks++) {
    if (ks + 1 < nsteps) {
      int k0n = (ks + 1) << 6;
      #pragma unroll
      for (int i = 0; i < 2; i++) gll16(gA[i] + k0n, &As[cur ^ 1][dofsA[i]]);
      #pragma unroll
      for (int i = 0; i < 4; i++) gll16(gB[i] + k0n, &Bs[cur ^ 1][dofsB[i]]);
      asm volatile("s_waitcnt vmcnt(6)" ::: "memory");
    } else {
      asm volatile("s_waitcnt vmcnt(0)" ::: "memory");
    }
    __builtin_amdgcn_s_barrier();
    #pragma unroll
    for (int kk = 0; kk < 2; kk++) {
      short8 af[2], bfv[4];
      #pragma unroll
      for (int i = 0; i < 2; i++) {
        int row = wm * 32 + i * 16 + (lane & 15);
        int ck = (kk * 4 + (lane >> 4)) ^ (row & 7);
        af[i] = *(const short8*)&As[cur][row * 64 + ck * 8];
      }
      #pragma unroll
      for (int j = 0; j < 4; j++) {
        int row = wn * 64 + j * 16 + (lane & 15);
        int ck = (kk * 4 + (lane >> 4)) ^ (row & 7);
        bfv[j] = *(const short8*)&Bs[cur][row * 64 + ck * 8];
      }
      #pragma unroll
      for (int i = 0; i < 2; i++)
        #pragma unroll
        for (int j = 0; j < 4; j++)
          acc[i][j] = __builtin_amdgcn_mfma_f32_16x16x32_bf16(af[i], bfv[j], acc[i][j], 0, 0, 0);
    }
    __builtin_amdgcn_s_barrier();
    cur ^= 1;
  }

  float bj[4]; int colb[4];
  #pragma unroll
  for (int j = 0; j < 4; j++) {
    colb[j] = bcol0 + wn * 64 + j * 16 + (lane & 15);
    bj[j] = bias[colb[j]];
  }
  #pragma unroll
  for (int i = 0; i < 2; i++) {
    #pragma unroll
    for (int r = 0; r < 4; r++) {
      int row = arow0 + wm * 32 + i * 16 + (lane >> 4) * 4 + r;
      #pragma unroll
      for (int j = 0; j < 4; j++)
        Cout[(size_t)row * Ncols + colb[j]] = f2bf(fmaxf(acc[i][j][r] + bj[j], 0.f));
    }
  }
}

// ---------- 32x256 GEMM + residual + LayerNorm, 256 thr; counted vmcnt(9) ----------
template<bool OUTBF>
__global__ __launch_bounds__(256) void k_gemm_ln(const ushort_t* __restrict__ A,
    const ushort_t* __restrict__ W, const float* __restrict__ bias,
    const float* __restrict__ R, const float* __restrict__ gamma,
    const float* __restrict__ beta, float* __restrict__ outF,
    ushort_t* __restrict__ outB, int Kdim) {
  __shared__ __align__(16) ushort_t As[2][32 * 64];    // 8KB
  __shared__ __align__(16) ushort_t Bs[2][256 * 64];   // 64KB
  __shared__ float red_s[32 * 4];
  __shared__ float red_q[32 * 4];
  int tid = threadIdx.x;
  int wid = tid >> 6, lane = tid & 63;
  int wn = wid;
  int row0 = blockIdx.x * 32;

  const ushort_t* gA; int dofsA;
  {
    int r = tid >> 3, ck = (tid & 7) ^ (r & 7);
    gA = A + (size_t)(row0 + r) * Kdim + ck * 8;
    dofsA = (wid * 64) * 8;
  }
  const ushort_t* gB[8]; int dofsB[8];
  #pragma unroll
  for (int i = 0; i < 8; i++) {
    int s = i * 256 + tid;
    int r = s >> 3, ck = (s & 7) ^ (r & 7);
    gB[i] = W + (size_t)r * Kdim + ck * 8;
    dofsB[i] = (i * 256 + wid * 64) * 8;
  }

  f32x4 acc[2][4];
  #pragma unroll
  for (int i = 0; i < 2; i++)
    #pragma unroll
    for (int n = 0; n < 4; n++) { f32x4 z = {0.f,0.f,0.f,0.f}; acc[i][n] = z; }

  gll16(gA, &As[0][dofsA]);
  #pragma unroll
  for (int i = 0; i < 8; i++) gll16(gB[i], &Bs[0][dofsB[i]]);
  asm volatile("s_waitcnt vmcnt(0)" ::: "memory");
  __builtin_amdgcn_s_barrier();

  int nsteps = Kdim >> 6;
  int cur = 0;
  for (int ks = 0; ks < nsteps; ks++) {
    if (ks + 1 < nsteps) {
      int k0n = (ks + 1) << 6;
      gll16(gA + k0n, &As[cur ^ 1][dofsA]);
      #pragma unroll
      for (int i = 0; i < 8; i++) gll16(gB[i] + k0n, &Bs[cur ^ 1][dofsB[i]]);
      asm volatile("s_waitcnt vmcnt(9)" ::: "memory");
    } else {
      asm volatile("s_waitcnt vmcnt(0)" ::: "memory");
    }
    __builtin_amdgcn_s_barrier();
    #pragma unroll
    for (int kk = 0; kk < 2; kk++) {
      short8 af[2], bfv[4];
      #pragma unroll
      for (int i = 0; i < 2; i++) {
        int row = i * 16 + (lane & 15);
        int ck = (kk * 4 + (lane >> 4)) ^ (row & 7);
        af[i] = *(const short8*)&As[cur][row * 64 + ck * 8];
      }
      #pragma unroll
      for (int n = 0; n < 4; n++) {
        int row = wn * 64 + n * 16 + (lane & 15);
        int ck = (kk * 4 + (lane >> 4)) ^ (row & 7);
        bfv[n] = *(const short8*)&Bs[cur][row * 64 + ck * 8];
      }
      #pragma unroll
      for (int i = 0; i < 2; i++)
        #pragma unroll
        for (int n = 0; n < 4; n++)
          acc[i][n] = __builtin_amdgcn_mfma_f32_16x16x32_bf16(af[i], bfv[n], acc[i][n], 0, 0, 0);
    }
    __builtin_amdgcn_s_barrier();
    cur ^= 1;
  }

  int col[4]; float bc[4], gm[4], bt[4];
  #pragma unroll
  for (int n = 0; n < 4; n++) {
    col[n] = wn * 64 + n * 16 + (lane & 15);
    bc[n] = bias[col[n]]; gm[n] = gamma[col[n]]; bt[n] = beta[col[n]];
  }
  #pragma unroll
  for (int i = 0; i < 2; i++) {
    #pragma unroll
    for (int r = 0; r < 4; r++) {
      int row_l = i * 16 + (lane >> 4) * 4 + r;
      const float* Rrow = R + (size_t)(row0 + row_l) * HD;
      float s = 0.f, q = 0.f;
      #pragma unroll
      for (int n = 0; n < 4; n++) {
        float v = acc[i][n][r] + bc[n] + Rrow[col[n]];
        acc[i][n][r] = v;
        s += v; q += v * v;
      }
      #pragma unroll
      for (int o = 1; o < 16; o <<= 1) { s += __shfl_xor(s, o, 64); q += __shfl_xor(q, o, 64); }
      if ((lane & 15) == 0) { red_s[row_l * 4 + wn] = s; red_q[row_l * 4 + wn] = q; }
    }
  }
  __syncthreads();
  #pragma unroll
  for (int i = 0; i < 2; i++) {
    #pragma unroll
    for (int r = 0; r < 4; r++) {
      int row_l = i * 16 + (lane >> 4) * 4 + r;
      float ssum = red_s[row_l * 4] + red_s[row_l * 4 + 1] + red_s[row_l * 4 + 2] + red_s[row_l * 4 + 3];
      float qsum = red_q[row_l * 4] + red_q[row_l * 4 + 1] + red_q[row_l * 4 + 2] + red_q[row_l * 4 + 3];
      float mu = ssum * (1.f / HD);
      float var = qsum * (1.f / HD) - mu * mu;
      float inv = rsqrtf(var + 1e-5f);
      size_t rb = (size_t)(row0 + row_l) * HD;
      #pragma unroll
      for (int n = 0; n < 4; n++) {
        float v = (acc[i][n][r] - mu) * inv * gm[n] + bt[n];
        outF[rb + col[n]] = v;
        if (OUTBF) outB[rb + col[n]] = f2bf(v);
      }
    }
  }
}

// ---------- fused masked attention, compact rows, analytic padding term ----------
__global__ __launch_bounds__(256) void k_attn(const ushort_t* __restrict__ qkb,
    const u32* __restrict__ adj, const int* __restrict__ offs,
    const float* __restrict__ bqk, ushort_t* __restrict__ attOb) {
  int bid = blockIdx.x;               // b(4b) | h(3b) | qtr(2b)
  int qtr = bid & 3, hh = (bid >> 2) & 7, b = bid >> 5;
  int nstart = offs[b], len = offs[b + 1] - nstart;
  int q0blk = qtr * 128;
  if (q0blk >= len) return;
  int lenT = len >> 5;

  __shared__ __align__(16) ushort_t K_lds[4 * 512 * 8];
  __shared__ __align__(16) ushort_t Kt_lds[64 * 32 * 8];
  __shared__ __align__(16) ushort_t P_lds[4 * 4 * 32 * 8];

  int tid = threadIdx.x;
  {
    const ushort_t* kg = qkb + (size_t)nstart * 512 + 256 + hh * 32;
    for (int t = tid; t < len; t += 256) {
      const uint4* src = (const uint4*)(kg + (size_t)t * 512);
      uint4 v0 = src[0], v1 = src[1], v2 = src[2], v3 = src[3];
      *(uint4*)&K_lds[0 * 4096 + t * 8] = v0;
      *(uint4*)&K_lds[1 * 4096 + t * 8] = v1;
      *(uint4*)&K_lds[2 * 4096 + t * 8] = v2;
      *(uint4*)&K_lds[3 * 4096 + t * 8] = v3;
    }
  }
  __syncthreads();
  {
    int d = tid & 31, tg = tid >> 5;
    int cc = d >> 3, e = d & 7;
    for (int i = 0; i < 8; i++) {
      int t0 = tg * 64 + i * 8;
      if (t0 < len) {
        u32 w0 = (u32)K_lds[cc * 4096 + (t0 + 0) * 8 + e] | ((u32)K_lds[cc * 4096 + (t0 + 1) * 8 + e] << 16);
        u32 w1 = (u32)K_lds[cc * 4096 + (t0 + 2) * 8 + e] | ((u32)K_lds[cc * 4096 + (t0 + 3) * 8 + e] << 16);
        u32 w2 = (u32)K_lds[cc * 4096 + (t0 + 4) * 8 + e] | ((u32)K_lds[cc * 4096 + (t0 + 5) * 8 + e] << 16);
        u32 w3 = (u32)K_lds[cc * 4096 + (t0 + 6) * 8 + e] | ((u32)K_lds[cc * 4096 + (t0 + 7) * 8 + e] << 16);
        uint4 pk = {w0, w1, w2, w3};
        *(uint4*)&Kt_lds[(t0 >> 3) * 256 + d * 8] = pk;
      }
    }
  }
  __syncthreads();

  int w = tid >> 6, lane = tid & 63;
  int q0w = q0blk + w * 32;
  if (q0w >= len) return;

  int lq = lane & 31, hf = lane >> 5;
  const float SCALE = 0.17677669529663687f;

  size_t qrow = (size_t)(nstart + q0w + lq) * 512 + hh * 32;
  short8 qf0 = *(const short8*)(qkb + qrow + hf * 8);
  short8 qf1 = *(const short8*)(qkb + qrow + 16 + hf * 8);

  const uint4* ap = (const uint4*)(adj + (size_t)(b * S_MAX + q0w + lq) * ADJW);
  uint4 a0 = ap[0], a1 = ap[1], a2 = ap[2], a3 = ap[3];
  u32 aw[16] = {a0.x, a0.y, a0.z, a0.w, a1.x, a1.y, a1.z, a1.w,
                a2.x, a2.y, a2.z, a2.w, a3.x, a3.y, a3.z, a3.w};

  f32x16 oacc = {0.f,0.f,0.f,0.f,0.f,0.f,0.f,0.f,0.f,0.f,0.f,0.f,0.f,0.f,0.f,0.f};
  float lsum = 0.f;

  for (int tt = 0; tt < lenT; tt++) {
    int t0 = tt * 32;
    short8 ka0 = *(const short8*)&K_lds[hf * 4096 + (t0 + lq) * 8];
    short8 ka1 = *(const short8*)&K_lds[(2 + hf) * 4096 + (t0 + lq) * 8];
    f32x16 sc = {0.f,0.f,0.f,0.f,0.f,0.f,0.f,0.f,0.f,0.f,0.f,0.f,0.f,0.f,0.f,0.f};
    sc = __builtin_amdgcn_mfma_f32_32x32x16_bf16(ka0, qf0, sc, 0, 0, 0);
    sc = __builtin_amdgcn_mfma_f32_32x32x16_bf16(ka1, qf1, sc, 0, 0, 0);
    u32 word = aw[tt];
    float p[16];
    #pragma unroll
    for (int r = 0; r < 16; r++) {
      int tb = (r & 3) + 8 * (r >> 2) + 4 * hf;
      float pe = __expf(sc[r] * SCALE);
      p[r] = ((word >> tb) & 1u) ? 0.f : pe;
      lsum += p[r];
    }
    #pragma unroll
    for (int g = 0; g < 4; g++) {
      u32 lo = (u32)f2bf(p[4 * g]) | ((u32)f2bf(p[4 * g + 1]) << 16);
      u32 hi = (u32)f2bf(p[4 * g + 2]) | ((u32)f2bf(p[4 * g + 3]) << 16);
      uint2 pk = {lo, hi};
      *(uint2*)&P_lds[w * 1024 + g * 256 + lq * 8 + hf * 4] = pk;
    }
    short8 va0 = *(const short8*)&Kt_lds[(t0 / 8 + hf) * 256 + lq * 8];
    short8 va1 = *(const short8*)&Kt_lds[(t0 / 8 + 2 + hf) * 256 + lq * 8];
    short8 pb0 = *(const short8*)&P_lds[w * 1024 + hf * 256 + lq * 8];
    short8 pb1 = *(const short8*)&P_lds[w * 1024 + (2 + hf) * 256 + lq * 8];
    oacc = __builtin_amdgcn_mfma_f32_32x32x16_bf16(va0, pb0, oacc, 0, 0, 0);
    oacc = __builtin_amdgcn_mfma_f32_32x32x16_bf16(va1, pb1, oacc, 0, 0, 0);
  }

  const float* bkh = bqk + 256 + hh * 32;
  float pq = 0.f;
  #pragma unroll
  for (int j = 0; j < 8; j++) pq += bf2f((ushort_t)qf0[j]) * bkh[hf * 8 + j];
  #pragma unroll
  for (int j = 0; j < 8; j++) pq += bf2f((ushort_t)qf1[j]) * bkh[16 + hf * 8 + j];
  pq += __shfl_xor(pq, 32, 64);
  float pe_pad = __expf(pq * SCALE) * (float)(S_MAX - len);

  float ltot = lsum + __shfl_xor(lsum, 32, 64) + pe_pad;
  float inv = 1.f / ltot;
  {
    int node = nstart + q0w + lq;
    ushort_t* op = attOb + (size_t)node * HD + hh * DH;
    #pragma unroll
    for (int g = 0; g < 4; g++) {
      float v0 = (oacc[4 * g]     + pe_pad * bkh[g * 8 + hf * 4 + 0]) * inv;
      float v1 = (oacc[4 * g + 1] + pe_pad * bkh[g * 8 + hf * 4 + 1]) * inv;
      float v2 = (oacc[4 * g + 2] + pe_pad * bkh[g * 8 + hf * 4 + 2]) * inv;
      float v3 = (oacc[4 * g + 3] + pe_pad * bkh[g * 8 + hf * 4 + 3]) * inv;
      u32 lo = (u32)f2bf(v0) | ((u32)f2bf(v1) << 16);
      u32 hi = (u32)f2bf(v2) | ((u32)f2bf(v3) << 16);
      uint2 pk = {lo, hi};
      *(uint2*)(op + g * 8 + hf * 4) = pk;
    }
  }
}

extern "C" void kernel_launch(void* const* d_in, const int* in_sizes, int n_in,
                              void* d_out, int out_size, void* d_ws, size_t ws_size,
                              hipStream_t stream) {
  const float* h   = (const float*)d_in[0];
  const float* Wq  = (const float*)d_in[1];
  const float* bq  = (const float*)d_in[2];
  const float* Wk  = (const float*)d_in[3];
  const float* bk  = (const float*)d_in[4];
  // d_in[5], d_in[6] (Wv, bv) unused: reference V uses the K projection
  const float* Wo  = (const float*)d_in[7];
  const float* bo  = (const float*)d_in[8];
  const float* W1  = (const float*)d_in[9];
  const float* b1  = (const float*)d_in[10];
  const float* W2  = (const float*)d_in[11];
  const float* b2  = (const float*)d_in[12];
  const float* g1  = (const float*)d_in[13];
  const float* be1 = (const float*)d_in[14];
  const float* g2  = (const float*)d_in[15];
  const float* be2 = (const float*)d_in[16];
  const int* batch = (const int*)d_in[17];
  const int* ei    = (const int*)d_in[18];
  int N = in_sizes[0] / HD;       // 6400
  int E = in_sizes[18] / 2;       // 102400

  char* ws = (char*)d_ws;
  ushort_t* hb    = (ushort_t*)(ws);                        // 3.2MB [6400,256] bf16 (later attO)
  ushort_t* attOb = hb;
  ushort_t* qkb   = (ushort_t*)(ws + ((size_t)4 << 20));    // 6.4MB [6400,512] bf16
  float*    h1    = (float*)(ws + ((size_t)12 << 20));      // 6.4MB fp32
  ushort_t* h1b   = (ushort_t*)(ws + ((size_t)19 << 20));   // 3.2MB
  ushort_t* ff1b  = (ushort_t*)(ws + ((size_t)23 << 20));   // 12.8MB
  char* wbase = ws + ((size_t)36 << 20);
  ushort_t* Wqkb = (ushort_t*)(wbase);                      // 256KB [512,256]
  ushort_t* Wob  = (ushort_t*)(wbase + (256 << 10));        // 128KB
  ushort_t* W1b  = (ushort_t*)(wbase + (384 << 10));        // 512KB [1024,256]
  ushort_t* W2b  = (ushort_t*)(wbase + (896 << 10));        // 512KB [256,1024]
  float*    bqk  = (float*)(wbase + (1408 << 10));          // 2KB  [512]
  u32*      adj  = (u32*)(wbase + (1536 << 10));            // 512KB
  int*      offs = (int*)(ws + ((size_t)38 << 20));         // 128B

  // P1: adj zero | offsets+bias | weight cvt | compact h cvt
  k_prep2<<<1281, 256, 0, stream>>>(adj, batch, N, offs, bq, bk, bqk,
                                    Wq, Wk, Wo, W1, W2,
                                    Wqkb, Wqkb + 65536, Wob, W1b, W2b, h, hb);
  // P2: fused Q|K projection + edge atomics
  k_qk<<<dim3(100, 4), 256, 0, stream>>>(hb, Wqkb, bqk, qkb, 100,
                                         ei, E, batch, offs, adj);
  // P3: attention (compact, analytic padding) -> attOb
  k_attn<<<B_G * NH * 4, 256, 0, stream>>>(qkb, adj, offs, bqk, attOb);
  // P4: out-proj + residual(h) + LN1 -> h1 (fp32) + h1b (bf16)
  k_gemm_ln<true><<<200, 256, 0, stream>>>(attOb, Wob, bo, h, g1, be1, h1, h1b, HD);
  // P5: FFN up + relu
  k_ffup<<<dim3(100, 8), 256, 0, stream>>>(h1b, W1b, b1, ff1b, FFD, HD);
  // P6: FFN down + residual(h1) + LN2 -> d_out (fp32)
  k_gemm_ln<false><<<200, 256, 0, stream>>>(ff1b, W2b, b2, h1, g2, be2, (float*)d_out, nullptr, FFD);
}

// Round 12
// 85.091 us; speedup vs baseline: 1.1163x; 1.0184x over previous
//
#include <hip/hip_runtime.h>
#include <math.h>

typedef unsigned int u32;
typedef unsigned short ushort_t;
typedef __attribute__((ext_vector_type(8))) short short8;
typedef __attribute__((ext_vector_type(4))) float f32x4;
typedef __attribute__((ext_vector_type(16))) float f32x16;
typedef __attribute__((ext_vector_type(4))) unsigned int u32x4;

#define B_G 16
#define S_MAX 512
#define NH 8
#define DH 32
#define HD 256
#define FFD 1024
#define ADJW 16            // u32 words per adjacency row (512 bits)

__device__ __forceinline__ ushort_t f2bf(float f) {
  u32 u = __float_as_uint(f);
  u += 0x7fffu + ((u >> 16) & 1u);
  return (ushort_t)(u >> 16);
}
__device__ __forceinline__ float bf2f(ushort_t s) {
  return __uint_as_float(((u32)s) << 16);
}

__device__ __forceinline__ void gll16(const void* g, void* l) {
  __builtin_amdgcn_global_load_lds(
      (const __attribute__((address_space(1))) unsigned int*)g,
      (__attribute__((address_space(3))) unsigned int*)l, 16, 0, 0);
}

// ---------- prep: zero adj | offsets+bias | weight cvt | h cvt (compact) ----------
__global__ __launch_bounds__(256) void k_prep2(u32* __restrict__ adj,
    const int* __restrict__ batch, int N, int* __restrict__ offs,
    const float* __restrict__ bq, const float* __restrict__ bk, float* __restrict__ bqk,
    const float* __restrict__ wa, const float* __restrict__ wb, const float* __restrict__ wc,
    const float* __restrict__ wd, const float* __restrict__ we,
    ushort_t* __restrict__ oa, ushort_t* __restrict__ ob, ushort_t* __restrict__ oc,
    ushort_t* __restrict__ od, ushort_t* __restrict__ oe,
    const float* __restrict__ h, ushort_t* __restrict__ hb) {
  int blk = blockIdx.x, tid = threadIdx.x;
  if (blk < 128) {
    uint4 z = {0u, 0u, 0u, 0u};
    ((uint4*)adj)[blk * 256 + tid] = z;
  } else if (blk == 128) {
    bqk[tid] = bq[tid];
    bqk[HD + tid] = bk[tid];
    if (tid <= B_G) {
      if (tid == B_G) { offs[B_G] = N; }
      else {
        int lo = 0, hi = N;
        while (lo < hi) { int mid = (lo + hi) >> 1; if (batch[mid] < tid) lo = mid + 1; else hi = mid; }
        offs[tid] = lo;
      }
    }
  } else if (blk < 481) {
    int bb = blk - 129;
    const float* src; ushort_t* dst; int off;
    if (bb < 32)       { src = wa; dst = oa; off = bb; }
    else if (bb < 64)  { src = wb; dst = ob; off = bb - 32; }
    else if (bb < 96)  { src = wc; dst = oc; off = bb - 64; }
    else if (bb < 224) { src = wd; dst = od; off = bb - 96; }
    else               { src = we; dst = oe; off = bb - 224; }
    size_t i = (size_t)off * 2048 + tid * 8;
    float4 v0 = *(const float4*)&src[i];
    float4 v1 = *(const float4*)&src[i + 4];
    uint4 pk;
    pk.x = (u32)f2bf(v0.x) | ((u32)f2bf(v0.y) << 16);
    pk.y = (u32)f2bf(v0.z) | ((u32)f2bf(v0.w) << 16);
    pk.z = (u32)f2bf(v1.x) | ((u32)f2bf(v1.y) << 16);
    pk.w = (u32)f2bf(v1.z) | ((u32)f2bf(v1.w) << 16);
    *(uint4*)&dst[i] = pk;
  } else {
    size_t i = ((size_t)(blk - 481) * 256 + tid) * 8;
    float4 v0 = *(const float4*)&h[i];
    float4 v1 = *(const float4*)&h[i + 4];
    uint4 pk;
    pk.x = (u32)f2bf(v0.x) | ((u32)f2bf(v0.y) << 16);
    pk.y = (u32)f2bf(v0.z) | ((u32)f2bf(v0.w) << 16);
    pk.z = (u32)f2bf(v1.x) | ((u32)f2bf(v1.y) << 16);
    pk.w = (u32)f2bf(v1.z) | ((u32)f2bf(v1.w) << 16);
    *(uint4*)&hb[i] = pk;
  }
}

// ---------- QK GEMM: 64x128 tile, BK=64, 256 thr; counted-vmcnt pipeline ----------
__global__ __launch_bounds__(256) void k_qk(const ushort_t* __restrict__ A,
    const ushort_t* __restrict__ W, const float* __restrict__ bias,
    ushort_t* __restrict__ Cout, int gridx,
    const int* __restrict__ ei, int E, const int* __restrict__ batch,
    const int* __restrict__ offs, u32* __restrict__ adj) {
  __shared__ __align__(16) ushort_t As[2][64 * 64];
  __shared__ __align__(16) ushort_t Bs[2][128 * 64];
  int tid = threadIdx.x;
  int wid = tid >> 6, lane = tid & 63;
  int wm = wid & 1, wn = wid >> 1;
  int arow0 = blockIdx.x * 64, bcol0 = blockIdx.y * 128;

  {
    int e = (blockIdx.y * gridx + blockIdx.x) * 256 + tid;
    if (e < E) {
      int s = ei[e], d = ei[E + e];
      int b = batch[s];
      int o = offs[b];
      atomicOr(&adj[(b * S_MAX + (s - o)) * ADJW + ((d - o) >> 5)], 1u << ((d - o) & 31));
    }
  }

  const ushort_t* gA[2]; const ushort_t* gB[4];
  int dofsA[2], dofsB[4];
  #pragma unroll
  for (int i = 0; i < 2; i++) {
    int s = i * 256 + wid * 64 + lane;
    int r = s >> 3, ck = (s & 7) ^ (r & 7);
    gA[i] = A + (size_t)(arow0 + r) * HD + ck * 8;
    dofsA[i] = (i * 256 + wid * 64) * 8;
  }
  #pragma unroll
  for (int i = 0; i < 4; i++) {
    int s = i * 256 + wid * 64 + lane;
    int r = s >> 3, ck = (s & 7) ^ (r & 7);
    gB[i] = W + (size_t)(bcol0 + r) * HD + ck * 8;
    dofsB[i] = (i * 256 + wid * 64) * 8;
  }

  f32x4 acc[2][4];
  #pragma unroll
  for (int i = 0; i < 2; i++)
    #pragma unroll
    for (int j = 0; j < 4; j++) { f32x4 z = {0.f,0.f,0.f,0.f}; acc[i][j] = z; }

  #pragma unroll
  for (int i = 0; i < 2; i++) gll16(gA[i], &As[0][dofsA[i]]);
  #pragma unroll
  for (int i = 0; i < 4; i++) gll16(gB[i], &Bs[0][dofsB[i]]);
  asm volatile("s_waitcnt vmcnt(0)" ::: "memory");
  __builtin_amdgcn_s_barrier();

  int cur = 0;
  for (int ks = 0; ks < 4; ks++) {
    if (ks < 3) {
      int k0n = (ks + 1) << 6;
      #pragma unroll
      for (int i = 0; i < 2; i++) gll16(gA[i] + k0n, &As[cur ^ 1][dofsA[i]]);
      #pragma unroll
      for (int i = 0; i < 4; i++) gll16(gB[i] + k0n, &Bs[cur ^ 1][dofsB[i]]);
      asm volatile("s_waitcnt vmcnt(6)" ::: "memory");
    } else {
      asm volatile("s_waitcnt vmcnt(0)" ::: "memory");
    }
    __builtin_amdgcn_s_barrier();
    #pragma unroll
    for (int kk = 0; kk < 2; kk++) {
      short8 af[2], bfv[4];
      #pragma unroll
      for (int i = 0; i < 2; i++) {
        int row = wm * 32 + i * 16 + (lane & 15);
        int ck = (kk * 4 + (lane >> 4)) ^ (row & 7);
        af[i] = *(const short8*)&As[cur][row * 64 + ck * 8];
      }
      #pragma unroll
      for (int j = 0; j < 4; j++) {
        int row = wn * 64 + j * 16 + (lane & 15);
        int ck = (kk * 4 + (lane >> 4)) ^ (row & 7);
        bfv[j] = *(const short8*)&Bs[cur][row * 64 + ck * 8];
      }
      #pragma unroll
      for (int i = 0; i < 2; i++)
        #pragma unroll
        for (int j = 0; j < 4; j++)
          acc[i][j] = __builtin_amdgcn_mfma_f32_16x16x32_bf16(af[i], bfv[j], acc[i][j], 0, 0, 0);
    }
    __builtin_amdgcn_s_barrier();
    cur ^= 1;
  }

  float bj[4]; int colb[4];
  #pragma unroll
  for (int j = 0; j < 4; j++) {
    colb[j] = bcol0 + wn * 64 + j * 16 + (lane & 15);
    bj[j] = bias[colb[j]];
  }
  #pragma unroll
  for (int i = 0; i < 2; i++) {
    #pragma unroll
    for (int r = 0; r < 4; r++) {
      int row = arow0 + wm * 32 + i * 16 + (lane >> 4) * 4 + r;
      #pragma unroll
      for (int j = 0; j < 4; j++)
        Cout[(size_t)row * 512 + colb[j]] = f2bf(acc[i][j][r] + bj[j]);
    }
  }
}

// ---------- FFN-up GEMM: 64x128 tile, BK=64, relu, bf16 out; counted vmcnt ----------
__global__ __launch_bounds__(256) void k_ffup(const ushort_t* __restrict__ A,
    const ushort_t* __restrict__ W, const float* __restrict__ bias,
    ushort_t* __restrict__ Cout, int Ncols, int Kdim) {
  __shared__ __align__(16) ushort_t As[2][64 * 64];
  __shared__ __align__(16) ushort_t Bs[2][128 * 64];
  int tid = threadIdx.x;
  int wid = tid >> 6, lane = tid & 63;
  int wm = wid & 1, wn = wid >> 1;
  int arow0 = blockIdx.x * 64, bcol0 = blockIdx.y * 128;

  const ushort_t* gA[2]; const ushort_t* gB[4];
  int dofsA[2], dofsB[4];
  #pragma unroll
  for (int i = 0; i < 2; i++) {
    int s = i * 256 + wid * 64 + lane;
    int r = s >> 3, ck = (s & 7) ^ (r & 7);
    gA[i] = A + (size_t)(arow0 + r) * Kdim + ck * 8;
    dofsA[i] = (i * 256 + wid * 64) * 8;
  }
  #pragma unroll
  for (int i = 0; i < 4; i++) {
    int s = i * 256 + wid * 64 + lane;
    int r = s >> 3, ck = (s & 7) ^ (r & 7);
    gB[i] = W + (size_t)(bcol0 + r) * Kdim + ck * 8;
    dofsB[i] = (i * 256 + wid * 64) * 8;
  }

  f32x4 acc[2][4];
  #pragma unroll
  for (int i = 0; i < 2; i++)
    #pragma unroll
    for (int j = 0; j < 4; j++) { f32x4 z = {0.f,0.f,0.f,0.f}; acc[i][j] = z; }

  #pragma unroll
  for (int i = 0; i < 2; i++) gll16(gA[i], &As[0][dofsA[i]]);
  #pragma unroll
  for (int i = 0; i < 4; i++) gll16(gB[i], &Bs[0][dofsB[i]]);
  asm volatile("s_waitcnt vmcnt(0)" ::: "memory");
  __builtin_amdgcn_s_barrier();

  int nsteps = Kdim >> 6;
  int cur = 0;
  for (int ks = 0; ks < nsteps; ks++) {
    if (ks + 1 < nsteps) {
      int k0n = (ks + 1) << 6;
      #pragma unroll
      for (int i = 0; i < 2; i++) gll16(gA[i] + k0n, &As[cur ^ 1][dofsA[i]]);
      #pragma unroll
      for (int i = 0; i < 4; i++) gll16(gB[i] + k0n, &Bs[cur ^ 1][dofsB[i]]);
      asm volatile("s_waitcnt vmcnt(6)" ::: "memory");
    } else {
      asm volatile("s_waitcnt vmcnt(0)" ::: "memory");
    }
    __builtin_amdgcn_s_barrier();
    #pragma unroll
    for (int kk = 0; kk < 2; kk++) {
      short8 af[2], bfv[4];
      #pragma unroll
      for (int i = 0; i < 2; i++) {
        int row = wm * 32 + i * 16 + (lane & 15);
        int ck = (kk * 4 + (lane >> 4)) ^ (row & 7);
        af[i] = *(const short8*)&As[cur][row * 64 + ck * 8];
      }
      #pragma unroll
      for (int j = 0; j < 4; j++) {
        int row = wn * 64 + j * 16 + (lane & 15);
        int ck = (kk * 4 + (lane >> 4)) ^ (row & 7);
        bfv[j] = *(const short8*)&Bs[cur][row * 64 + ck * 8];
      }
      #pragma unroll
      for (int i = 0; i < 2; i++)
        #pragma unroll
        for (int j = 0; j < 4; j++)
          acc[i][j] = __builtin_amdgcn_mfma_f32_16x16x32_bf16(af[i], bfv[j], acc[i][j], 0, 0, 0);
    }
    __builtin_amdgcn_s_barrier();
    cur ^= 1;
  }

  float bj[4]; int colb[4];
  #pragma unroll
  for (int j = 0; j < 4; j++) {
    colb[j] = bcol0 + wn * 64 + j * 16 + (lane & 15);
    bj[j] = bias[colb[j]];
  }
  #pragma unroll
  for (int i = 0; i < 2; i++) {
    #pragma unroll
    for (int r = 0; r < 4; r++) {
      int row = arow0 + wm * 32 + i * 16 + (lane >> 4) * 4 + r;
      #pragma unroll
      for (int j = 0; j < 4; j++)
        Cout[(size_t)row * Ncols + colb[j]] = f2bf(fmaxf(acc[i][j][r] + bj[j], 0.f));
    }
  }
}

// ---------- 32x256 GEMM + residual + LayerNorm, 256 thr; counted vmcnt(9) ----------
// OUTF: write fp32 out; OUTBF: write bf16 out; RESBF: residual is bf16 (else fp32)
template<bool OUTF, bool OUTBF, bool RESBF>
__global__ __launch_bounds__(256) void k_gemm_ln(const ushort_t* __restrict__ A,
    const ushort_t* __restrict__ W, const float* __restrict__ bias,
    const void* __restrict__ R, const float* __restrict__ gamma,
    const float* __restrict__ beta, float* __restrict__ outF,
    ushort_t* __restrict__ outB, int Kdim) {
  __shared__ __align__(16) ushort_t As[2][32 * 64];    // 8KB
  __shared__ __align__(16) ushort_t Bs[2][256 * 64];   // 64KB
  __shared__ float red_s[32 * 4];
  __shared__ float red_q[32 * 4];
  int tid = threadIdx.x;
  int wid = tid >> 6, lane = tid & 63;
  int wn = wid;
  int row0 = blockIdx.x * 32;

  const ushort_t* gA; int dofsA;
  {
    int r = tid >> 3, ck = (tid & 7) ^ (r & 7);
    gA = A + (size_t)(row0 + r) * Kdim + ck * 8;
    dofsA = (wid * 64) * 8;
  }
  const ushort_t* gB[8]; int dofsB[8];
  #pragma unroll
  for (int i = 0; i < 8; i++) {
    int s = i * 256 + tid;
    int r = s >> 3, ck = (s & 7) ^ (r & 7);
    gB[i] = W + (size_t)r * Kdim + ck * 8;
    dofsB[i] = (i * 256 + wid * 64) * 8;
  }

  f32x4 acc[2][4];
  #pragma unroll
  for (int i = 0; i < 2; i++)
    #pragma unroll
    for (int n = 0; n < 4; n++) { f32x4 z = {0.f,0.f,0.f,0.f}; acc[i][n] = z; }

  gll16(gA, &As[0][dofsA]);
  #pragma unroll
  for (int i = 0; i < 8; i++) gll16(gB[i], &Bs[0][dofsB[i]]);
  asm volatile("s_waitcnt vmcnt(0)" ::: "memory");
  __builtin_amdgcn_s_barrier();

  int nsteps = Kdim >> 6;
  int cur = 0;
  for (int ks = 0; ks < nsteps; ks++) {
    if (ks + 1 < nsteps) {
      int k0n = (ks + 1) << 6;
      gll16(gA + k0n, &As[cur ^ 1][dofsA]);
      #pragma unroll
      for (int i = 0; i < 8; i++) gll16(gB[i] + k0n, &Bs[cur ^ 1][dofsB[i]]);
      asm volatile("s_waitcnt vmcnt(9)" ::: "memory");
    } else {
      asm volatile("s_waitcnt vmcnt(0)" ::: "memory");
    }
    __builtin_amdgcn_s_barrier();
    #pragma unroll
    for (int kk = 0; kk < 2; kk++) {
      short8 af[2], bfv[4];
      #pragma unroll
      for (int i = 0; i < 2; i++) {
        int row = i * 16 + (lane & 15);
        int ck = (kk * 4 + (lane >> 4)) ^ (row & 7);
        af[i] = *(const short8*)&As[cur][row * 64 + ck * 8];
      }
      #pragma unroll
      for (int n = 0; n < 4; n++) {
        int row = wn * 64 + n * 16 + (lane & 15);
        int ck = (kk * 4 + (lane >> 4)) ^ (row & 7);
        bfv[n] = *(const short8*)&Bs[cur][row * 64 + ck * 8];
      }
      #pragma unroll
      for (int i = 0; i < 2; i++)
        #pragma unroll
        for (int n = 0; n < 4; n++)
          acc[i][n] = __builtin_amdgcn_mfma_f32_16x16x32_bf16(af[i], bfv[n], acc[i][n], 0, 0, 0);
    }
    __builtin_amdgcn_s_barrier();
    cur ^= 1;
  }

  int col[4]; float bc[4], gm[4], bt[4];
  #pragma unroll
  for (int n = 0; n < 4; n++) {
    col[n] = wn * 64 + n * 16 + (lane & 15);
    bc[n] = bias[col[n]]; gm[n] = gamma[col[n]]; bt[n] = beta[col[n]];
  }
  #pragma unroll
  for (int i = 0; i < 2; i++) {
    #pragma unroll
    for (int r = 0; r < 4; r++) {
      int row_l = i * 16 + (lane >> 4) * 4 + r;
      size_t rbase = (size_t)(row0 + row_l) * HD;
      float s = 0.f, q = 0.f;
      #pragma unroll
      for (int n = 0; n < 4; n++) {
        float rv = RESBF ? bf2f(((const ushort_t*)R)[rbase + col[n]])
                         : ((const float*)R)[rbase + col[n]];
        float v = acc[i][n][r] + bc[n] + rv;
        acc[i][n][r] = v;
        s += v; q += v * v;
      }
      #pragma unroll
      for (int o = 1; o < 16; o <<= 1) { s += __shfl_xor(s, o, 64); q += __shfl_xor(q, o, 64); }
      if ((lane & 15) == 0) { red_s[row_l * 4 + wn] = s; red_q[row_l * 4 + wn] = q; }
    }
  }
  __syncthreads();
  #pragma unroll
  for (int i = 0; i < 2; i++) {
    #pragma unroll
    for (int r = 0; r < 4; r++) {
      int row_l = i * 16 + (lane >> 4) * 4 + r;
      float ssum = red_s[row_l * 4] + red_s[row_l * 4 + 1] + red_s[row_l * 4 + 2] + red_s[row_l * 4 + 3];
      float qsum = red_q[row_l * 4] + red_q[row_l * 4 + 1] + red_q[row_l * 4 + 2] + red_q[row_l * 4 + 3];
      float mu = ssum * (1.f / HD);
      float var = qsum * (1.f / HD) - mu * mu;
      float inv = rsqrtf(var + 1e-5f);
      size_t rb = (size_t)(row0 + row_l) * HD;
      #pragma unroll
      for (int n = 0; n < 4; n++) {
        float v = (acc[i][n][r] - mu) * inv * gm[n] + bt[n];
        if (OUTF) outF[rb + col[n]] = v;
        if (OUTBF) outB[rb + col[n]] = f2bf(v);
      }
    }
  }
}

// ---------- fused masked attention: 512 thr, (b,h,half) blocks, permlane PV ----------
// QK^T swapped (lane owns q-col). PV B-operand built IN-REGISTER: the C-layout
// t-slots {4hf+0..3, 8+4hf+0..3} become the contiguous B-frag {8hf+0..7} via
// v_permlane32_swap_b32 (each swap yields both needed words). No P_lds.
__global__ __launch_bounds__(512) void k_attn(const ushort_t* __restrict__ qkb,
    const u32* __restrict__ adj, const int* __restrict__ offs,
    const float* __restrict__ bqk, ushort_t* __restrict__ attOb) {
  int bid = blockIdx.x;               // b(4b) | h(3b) | half(1b)
  int half = bid & 1, hh = (bid >> 1) & 7, b = bid >> 4;
  int nstart = offs[b], len = offs[b + 1] - nstart;
  int lenT = len >> 5;                // len % 32 == 0

  __shared__ __align__(16) ushort_t K_lds[4 * 512 * 8];    // 32KB [cc][t][8]
  __shared__ __align__(16) ushort_t Kt_lds[64 * 32 * 8];   // 32KB [tchunk][d][8]

  int tid = threadIdx.x;
  {
    const ushort_t* kg = qkb + (size_t)nstart * 512 + 256 + hh * 32;
    for (int t = tid; t < len; t += 512) {
      const uint4* src = (const uint4*)(kg + (size_t)t * 512);
      uint4 v0 = src[0], v1 = src[1], v2 = src[2], v3 = src[3];
      *(uint4*)&K_lds[0 * 4096 + t * 8] = v0;
      *(uint4*)&K_lds[1 * 4096 + t * 8] = v1;
      *(uint4*)&K_lds[2 * 4096 + t * 8] = v2;
      *(uint4*)&K_lds[3 * 4096 + t * 8] = v3;
    }
  }
  __syncthreads();
  {
    int d = tid & 31, tg = tid >> 5;          // tg in [0,16)
    int cc = d >> 3, e = d & 7;
    #pragma unroll
    for (int i = 0; i < 4; i++) {
      int t0 = tg * 32 + i * 8;
      if (t0 < len) {
        u32 w0 = (u32)K_lds[cc * 4096 + (t0 + 0) * 8 + e] | ((u32)K_lds[cc * 4096 + (t0 + 1) * 8 + e] << 16);
        u32 w1 = (u32)K_lds[cc * 4096 + (t0 + 2) * 8 + e] | ((u32)K_lds[cc * 4096 + (t0 + 3) * 8 + e] << 16);
        u32 w2 = (u32)K_lds[cc * 4096 + (t0 + 4) * 8 + e] | ((u32)K_lds[cc * 4096 + (t0 + 5) * 8 + e] << 16);
        u32 w3 = (u32)K_lds[cc * 4096 + (t0 + 6) * 8 + e] | ((u32)K_lds[cc * 4096 + (t0 + 7) * 8 + e] << 16);
        uint4 pk = {w0, w1, w2, w3};
        *(uint4*)&Kt_lds[(t0 >> 3) * 256 + d * 8] = pk;
      }
    }
  }
  __syncthreads();

  int w = tid >> 6, lane = tid & 63;
  int q0w = half * 256 + w * 32;
  if (q0w >= len) return;   // no barriers below (wave-uniform)

  int lq = lane & 31, hf = lane >> 5;
  const float SCALE = 0.17677669529663687f;  // 1/sqrt(32)

  size_t qrow = (size_t)(nstart + q0w + lq) * 512 + hh * 32;
  short8 qf0 = *(const short8*)(qkb + qrow + hf * 8);
  short8 qf1 = *(const short8*)(qkb + qrow + 16 + hf * 8);

  const uint4* ap = (const uint4*)(adj + (size_t)(b * S_MAX + q0w + lq) * ADJW);
  uint4 a0 = ap[0], a1 = ap[1], a2 = ap[2], a3 = ap[3];
  u32 aw[16] = {a0.x, a0.y, a0.z, a0.w, a1.x, a1.y, a1.z, a1.w,
                a2.x, a2.y, a2.z, a2.w, a3.x, a3.y, a3.z, a3.w};

  f32x16 oacc = {0.f,0.f,0.f,0.f,0.f,0.f,0.f,0.f,0.f,0.f,0.f,0.f,0.f,0.f,0.f,0.f};
  float lsum = 0.f;

  for (int tt = 0; tt < lenT; tt++) {
    int t0 = tt * 32;
    short8 ka0 = *(const short8*)&K_lds[hf * 4096 + (t0 + lq) * 8];
    short8 ka1 = *(const short8*)&K_lds[(2 + hf) * 4096 + (t0 + lq) * 8];
    f32x16 sc = {0.f,0.f,0.f,0.f,0.f,0.f,0.f,0.f,0.f,0.f,0.f,0.f,0.f,0.f,0.f,0.f};
    sc = __builtin_amdgcn_mfma_f32_32x32x16_bf16(ka0, qf0, sc, 0, 0, 0);
    sc = __builtin_amdgcn_mfma_f32_32x32x16_bf16(ka1, qf1, sc, 0, 0, 0);
    u32 word = aw[tt];
    float p[16];
    #pragma unroll
    for (int r = 0; r < 16; r++) {
      int tb = (r & 3) + 8 * (r >> 2) + 4 * hf;
      float pe = __expf(sc[r] * SCALE);
      p[r] = ((word >> tb) & 1u) ? 0.f : pe;
      lsum += p[r];
    }
    // pack P^T to bf16 pairs; permlane32_swap builds both B-frag halves at once
    u32 q0 = (u32)f2bf(p[0])  | ((u32)f2bf(p[1])  << 16);
    u32 q1 = (u32)f2bf(p[2])  | ((u32)f2bf(p[3])  << 16);
    u32 q2 = (u32)f2bf(p[4])  | ((u32)f2bf(p[5])  << 16);
    u32 q3 = (u32)f2bf(p[6])  | ((u32)f2bf(p[7])  << 16);
    u32 q4 = (u32)f2bf(p[8])  | ((u32)f2bf(p[9])  << 16);
    u32 q5 = (u32)f2bf(p[10]) | ((u32)f2bf(p[11]) << 16);
    u32 q6 = (u32)f2bf(p[12]) | ((u32)f2bf(p[13]) << 16);
    u32 q7 = (u32)f2bf(p[14]) | ((u32)f2bf(p[15]) << 16);
    asm volatile("v_permlane32_swap_b32 %0, %1" : "+v"(q0), "+v"(q2));
    asm volatile("v_permlane32_swap_b32 %0, %1" : "+v"(q1), "+v"(q3));
    asm volatile("v_permlane32_swap_b32 %0, %1" : "+v"(q4), "+v"(q6));
    asm volatile("v_permlane32_swap_b32 %0, %1" : "+v"(q5), "+v"(q7));
    u32x4 f0v = {q0, q1, q2, q3};
    u32x4 f1v = {q4, q5, q6, q7};
    short8 pb0 = __builtin_bit_cast(short8, f0v);
    short8 pb1 = __builtin_bit_cast(short8, f1v);
    short8 va0 = *(const short8*)&Kt_lds[(t0 / 8 + hf) * 256 + lq * 8];
    short8 va1 = *(const short8*)&Kt_lds[(t0 / 8 + 2 + hf) * 256 + lq * 8];
    oacc = __builtin_amdgcn_mfma_f32_32x32x16_bf16(va0, pb0, oacc, 0, 0, 0);
    oacc = __builtin_amdgcn_mfma_f32_32x32x16_bf16(va1, pb1, oacc, 0, 0, 0);
  }

  const float* bkh = bqk + 256 + hh * 32;
  float pq = 0.f;
  #pragma unroll
  for (int j = 0; j < 8; j++) pq += bf2f((ushort_t)qf0[j]) * bkh[hf * 8 + j];
  #pragma unroll
  for (int j = 0; j < 8; j++) pq += bf2f((ushort_t)qf1[j]) * bkh[16 + hf * 8 + j];
  pq += __shfl_xor(pq, 32, 64);
  float pe_pad = __expf(pq * SCALE) * (float)(S_MAX - len);

  float ltot = lsum + __shfl_xor(lsum, 32, 64) + pe_pad;
  float inv = 1.f / ltot;
  {
    int node = nstart + q0w + lq;
    ushort_t* op = attOb + (size_t)node * HD + hh * DH;
    #pragma unroll
    for (int g = 0; g < 4; g++) {
      float v0 = (oacc[4 * g]     + pe_pad * bkh[g * 8 + hf * 4 + 0]) * inv;
      float v1 = (oacc[4 * g + 1] + pe_pad * bkh[g * 8 + hf * 4 + 1]) * inv;
      float v2 = (oacc[4 * g + 2] + pe_pad * bkh[g * 8 + hf * 4 + 2]) * inv;
      float v3 = (oacc[4 * g + 3] + pe_pad * bkh[g * 8 + hf * 4 + 3]) * inv;
      u32 lo = (u32)f2bf(v0) | ((u32)f2bf(v1) << 16);
      u32 hi = (u32)f2bf(v2) | ((u32)f2bf(v3) << 16);
      uint2 pk = {lo, hi};
      *(uint2*)(op + g * 8 + hf * 4) = pk;
    }
  }
}

extern "C" void kernel_launch(void* const* d_in, const int* in_sizes, int n_in,
                              void* d_out, int out_size, void* d_ws, size_t ws_size,
                              hipStream_t stream) {
  const float* h   = (const float*)d_in[0];
  const float* Wq  = (const float*)d_in[1];
  const float* bq  = (const float*)d_in[2];
  const float* Wk  = (const float*)d_in[3];
  const float* bk  = (const float*)d_in[4];
  // d_in[5], d_in[6] (Wv, bv) unused: reference V uses the K projection
  const float* Wo  = (const float*)d_in[7];
  const float* bo  = (const float*)d_in[8];
  const float* W1  = (const float*)d_in[9];
  const float* b1  = (const float*)d_in[10];
  const float* W2  = (const float*)d_in[11];
  const float* b2  = (const float*)d_in[12];
  const float* g1  = (const float*)d_in[13];
  const float* be1 = (const float*)d_in[14];
  const float* g2  = (const float*)d_in[15];
  const float* be2 = (const float*)d_in[16];
  const int* batch = (const int*)d_in[17];
  const int* ei    = (const int*)d_in[18];
  int N = in_sizes[0] / HD;       // 6400
  int E = in_sizes[18] / 2;       // 102400

  char* ws = (char*)d_ws;
  ushort_t* hb    = (ushort_t*)(ws);                        // 3.2MB [6400,256] bf16 (later attO)
  ushort_t* attOb = hb;
  ushort_t* qkb   = (ushort_t*)(ws + ((size_t)4 << 20));    // 6.4MB [6400,512] bf16
  ushort_t* h1b   = (ushort_t*)(ws + ((size_t)19 << 20));   // 3.2MB bf16 (LN1 out + residual)
  ushort_t* ff1b  = (ushort_t*)(ws + ((size_t)23 << 20));   // 12.8MB
  char* wbase = ws + ((size_t)36 << 20);
  ushort_t* Wqkb = (ushort_t*)(wbase);                      // 256KB [512,256]
  ushort_t* Wob  = (ushort_t*)(wbase + (256 << 10));        // 128KB
  ushort_t* W1b  = (ushort_t*)(wbase + (384 << 10));        // 512KB [1024,256]
  ushort_t* W2b  = (ushort_t*)(wbase + (896 << 10));        // 512KB [256,1024]
  float*    bqk  = (float*)(wbase + (1408 << 10));          // 2KB  [512]
  u32*      adj  = (u32*)(wbase + (1536 << 10));            // 512KB
  int*      offs = (int*)(ws + ((size_t)38 << 20));         // 128B

  // P1: adj zero | offsets+bias | weight cvt | compact h cvt
  k_prep2<<<1281, 256, 0, stream>>>(adj, batch, N, offs, bq, bk, bqk,
                                    Wq, Wk, Wo, W1, W2,
                                    Wqkb, Wqkb + 65536, Wob, W1b, W2b, h, hb);
  // P2: fused Q|K projection + edge atomics
  k_qk<<<dim3(100, 4), 256, 0, stream>>>(hb, Wqkb, bqk, qkb, 100,
                                         ei, E, batch, offs, adj);
  // P3: attention (512 thr, permlane PV) -> attOb
  k_attn<<<B_G * NH * 2, 512, 0, stream>>>(qkb, adj, offs, bqk, attOb);
  // P4: out-proj + residual(h fp32) + LN1 -> h1b (bf16 only)
  k_gemm_ln<false, true, false><<<200, 256, 0, stream>>>(attOb, Wob, bo, h, g1, be1,
                                                         nullptr, h1b, HD);
  // P5: FFN up + relu
  k_ffup<<<dim3(100, 8), 256, 0, stream>>>(h1b, W1b, b1, ff1b, FFD, HD);
  // P6: FFN down + residual(h1b bf16) + LN2 -> d_out (fp32)
  k_gemm_ln<true, false, true><<<200, 256, 0, stream>>>(ff1b, W2b, b2, h1b, g2, be2,
                                                        (float*)d_out, nullptr, FFD);
}

// Round 14
// 84.348 us; speedup vs baseline: 1.1262x; 1.0088x over previous
//
#include <hip/hip_runtime.h>
#include <math.h>

typedef unsigned int u32;
typedef unsigned short ushort_t;
typedef __attribute__((ext_vector_type(8))) short short8;
typedef __attribute__((ext_vector_type(4))) float f32x4;
typedef __attribute__((ext_vector_type(16))) float f32x16;
typedef __attribute__((ext_vector_type(4))) unsigned int u32x4;

#define B_G 16
#define S_MAX 512
#define NH 8
#define DH 32
#define HD 256
#define FFD 1024
#define ADJW 16            // u32 words per adjacency row (512 bits)

__device__ __forceinline__ ushort_t f2bf(float f) {
  u32 u = __float_as_uint(f);
  u += 0x7fffu + ((u >> 16) & 1u);
  return (ushort_t)(u >> 16);
}
__device__ __forceinline__ float bf2f(ushort_t s) {
  return __uint_as_float(((u32)s) << 16);
}

__device__ __forceinline__ void gll16(const void* g, void* l) {
  __builtin_amdgcn_global_load_lds(
      (const __attribute__((address_space(1))) unsigned int*)g,
      (__attribute__((address_space(3))) unsigned int*)l, 16, 0, 0);
}

// ---------- prep: zero adj | offsets+bias | weight cvt | h cvt (compact) ----------
__global__ __launch_bounds__(256) void k_prep2(u32* __restrict__ adj,
    const int* __restrict__ batch, int N, int* __restrict__ offs,
    const float* __restrict__ bq, const float* __restrict__ bk, float* __restrict__ bqk,
    const float* __restrict__ wa, const float* __restrict__ wb, const float* __restrict__ wc,
    const float* __restrict__ wd, const float* __restrict__ we,
    ushort_t* __restrict__ oa, ushort_t* __restrict__ ob, ushort_t* __restrict__ oc,
    ushort_t* __restrict__ od, ushort_t* __restrict__ oe,
    const float* __restrict__ h, ushort_t* __restrict__ hb) {
  int blk = blockIdx.x, tid = threadIdx.x;
  if (blk < 128) {
    uint4 z = {0u, 0u, 0u, 0u};
    ((uint4*)adj)[blk * 256 + tid] = z;
  } else if (blk == 128) {
    bqk[tid] = bq[tid];
    bqk[HD + tid] = bk[tid];
    if (tid <= B_G) {
      if (tid == B_G) { offs[B_G] = N; }
      else {
        int lo = 0, hi = N;
        while (lo < hi) { int mid = (lo + hi) >> 1; if (batch[mid] < tid) lo = mid + 1; else hi = mid; }
        offs[tid] = lo;
      }
    }
  } else if (blk < 481) {
    int bb = blk - 129;
    const float* src; ushort_t* dst; int off;
    if (bb < 32)       { src = wa; dst = oa; off = bb; }
    else if (bb < 64)  { src = wb; dst = ob; off = bb - 32; }
    else if (bb < 96)  { src = wc; dst = oc; off = bb - 64; }
    else if (bb < 224) { src = wd; dst = od; off = bb - 96; }
    else               { src = we; dst = oe; off = bb - 224; }
    size_t i = (size_t)off * 2048 + tid * 8;
    float4 v0 = *(const float4*)&src[i];
    float4 v1 = *(const float4*)&src[i + 4];
    uint4 pk;
    pk.x = (u32)f2bf(v0.x) | ((u32)f2bf(v0.y) << 16);
    pk.y = (u32)f2bf(v0.z) | ((u32)f2bf(v0.w) << 16);
    pk.z = (u32)f2bf(v1.x) | ((u32)f2bf(v1.y) << 16);
    pk.w = (u32)f2bf(v1.z) | ((u32)f2bf(v1.w) << 16);
    *(uint4*)&dst[i] = pk;
  } else {
    size_t i = ((size_t)(blk - 481) * 256 + tid) * 8;
    float4 v0 = *(const float4*)&h[i];
    float4 v1 = *(const float4*)&h[i + 4];
    uint4 pk;
    pk.x = (u32)f2bf(v0.x) | ((u32)f2bf(v0.y) << 16);
    pk.y = (u32)f2bf(v0.z) | ((u32)f2bf(v0.w) << 16);
    pk.z = (u32)f2bf(v1.x) | ((u32)f2bf(v1.y) << 16);
    pk.w = (u32)f2bf(v1.z) | ((u32)f2bf(v1.w) << 16);
    *(uint4*)&hb[i] = pk;
  }
}

// ---------- QK GEMM: 64x128 tile, BK=64, 256 thr; counted-vmcnt pipeline ----------
__global__ __launch_bounds__(256) void k_qk(const ushort_t* __restrict__ A,
    const ushort_t* __restrict__ W, const float* __restrict__ bias,
    ushort_t* __restrict__ Cout, int gridx,
    const int* __restrict__ ei, int E, const int* __restrict__ batch,
    const int* __restrict__ offs, u32* __restrict__ adj) {
  __shared__ __align__(16) ushort_t As[2][64 * 64];
  __shared__ __align__(16) ushort_t Bs[2][128 * 64];
  int tid = threadIdx.x;
  int wid = tid >> 6, lane = tid & 63;
  int wm = wid & 1, wn = wid >> 1;
  int arow0 = blockIdx.x * 64, bcol0 = blockIdx.y * 128;

  {
    int e = (blockIdx.y * gridx + blockIdx.x) * 256 + tid;
    if (e < E) {
      int s = ei[e], d = ei[E + e];
      int b = batch[s];
      int o = offs[b];
      atomicOr(&adj[(b * S_MAX + (s - o)) * ADJW + ((d - o) >> 5)], 1u << ((d - o) & 31));
    }
  }

  const ushort_t* gA[2]; const ushort_t* gB[4];
  int dofsA[2], dofsB[4];
  #pragma unroll
  for (int i = 0; i < 2; i++) {
    int s = i * 256 + wid * 64 + lane;
    int r = s >> 3, ck = (s & 7) ^ (r & 7);
    gA[i] = A + (size_t)(arow0 + r) * HD + ck * 8;
    dofsA[i] = (i * 256 + wid * 64) * 8;
  }
  #pragma unroll
  for (int i = 0; i < 4; i++) {
    int s = i * 256 + wid * 64 + lane;
    int r = s >> 3, ck = (s & 7) ^ (r & 7);
    gB[i] = W + (size_t)(bcol0 + r) * HD + ck * 8;
    dofsB[i] = (i * 256 + wid * 64) * 8;
  }

  f32x4 acc[2][4];
  #pragma unroll
  for (int i = 0; i < 2; i++)
    #pragma unroll
    for (int j = 0; j < 4; j++) { f32x4 z = {0.f,0.f,0.f,0.f}; acc[i][j] = z; }

  #pragma unroll
  for (int i = 0; i < 2; i++) gll16(gA[i], &As[0][dofsA[i]]);
  #pragma unroll
  for (int i = 0; i < 4; i++) gll16(gB[i], &Bs[0][dofsB[i]]);
  asm volatile("s_waitcnt vmcnt(0)" ::: "memory");
  __builtin_amdgcn_s_barrier();

  int cur = 0;
  for (int ks = 0; ks < 4; ks++) {
    if (ks < 3) {
      int k0n = (ks + 1) << 6;
      #pragma unroll
      for (int i = 0; i < 2; i++) gll16(gA[i] + k0n, &As[cur ^ 1][dofsA[i]]);
      #pragma unroll
      for (int i = 0; i < 4; i++) gll16(gB[i] + k0n, &Bs[cur ^ 1][dofsB[i]]);
      asm volatile("s_waitcnt vmcnt(6)" ::: "memory");
    } else {
      asm volatile("s_waitcnt vmcnt(0)" ::: "memory");
    }
    __builtin_amdgcn_s_barrier();
    #pragma unroll
    for (int kk = 0; kk < 2; kk++) {
      short8 af[2], bfv[4];
      #pragma unroll
      for (int i = 0; i < 2; i++) {
        int row = wm * 32 + i * 16 + (lane & 15);
        int ck = (kk * 4 + (lane >> 4)) ^ (row & 7);
        af[i] = *(const short8*)&As[cur][row * 64 + ck * 8];
      }
      #pragma unroll
      for (int j = 0; j < 4; j++) {
        int row = wn * 64 + j * 16 + (lane & 15);
        int ck = (kk * 4 + (lane >> 4)) ^ (row & 7);
        bfv[j] = *(const short8*)&Bs[cur][row * 64 + ck * 8];
      }
      #pragma unroll
      for (int i = 0; i < 2; i++)
        #pragma unroll
        for (int j = 0; j < 4; j++)
          acc[i][j] = __builtin_amdgcn_mfma_f32_16x16x32_bf16(af[i], bfv[j], acc[i][j], 0, 0, 0);
    }
    __builtin_amdgcn_s_barrier();
    cur ^= 1;
  }

  float bj[4]; int colb[4];
  #pragma unroll
  for (int j = 0; j < 4; j++) {
    colb[j] = bcol0 + wn * 64 + j * 16 + (lane & 15);
    bj[j] = bias[colb[j]];
  }
  #pragma unroll
  for (int i = 0; i < 2; i++) {
    #pragma unroll
    for (int r = 0; r < 4; r++) {
      int row = arow0 + wm * 32 + i * 16 + (lane >> 4) * 4 + r;
      #pragma unroll
      for (int j = 0; j < 4; j++)
        Cout[(size_t)row * 512 + colb[j]] = f2bf(acc[i][j][r] + bj[j]);
    }
  }
}

// ---------- FFN-up GEMM: 128x128 tile, 4 waves (2x2), acc[4][4], BK=64 ----------
// Ratio fix: 8 ds_read_b128 per kk feed 16 MFMA (2.0 MFMA/read vs 1.33 at
// 64x128) -- inner loop was LDS-read-bound. Grid (50,8)=400, LDS 64KB (2/CU),
// counted vmcnt(8) double-buffer.
__global__ __launch_bounds__(256) void k_ffup(const ushort_t* __restrict__ A,
    const ushort_t* __restrict__ W, const float* __restrict__ bias,
    ushort_t* __restrict__ Cout, int Ncols, int Kdim) {
  __shared__ __align__(16) ushort_t As[2][128 * 64];   // 32KB
  __shared__ __align__(16) ushort_t Bs[2][128 * 64];   // 32KB
  int tid = threadIdx.x;
  int wid = tid >> 6, lane = tid & 63;
  int wm = wid & 1, wn = wid >> 1;
  int arow0 = blockIdx.x * 128, bcol0 = blockIdx.y * 128;

  const ushort_t* gA[4]; const ushort_t* gB[4];
  int dofs[4];
  #pragma unroll
  for (int i = 0; i < 4; i++) {
    int s = i * 256 + tid;
    int r = s >> 3, ck = (s & 7) ^ (r & 7);
    gA[i] = A + (size_t)(arow0 + r) * Kdim + ck * 8;
    gB[i] = W + (size_t)(bcol0 + r) * Kdim + ck * 8;
    dofs[i] = (i * 256 + wid * 64) * 8;
  }

  f32x4 acc[4][4];
  #pragma unroll
  for (int i = 0; i < 4; i++)
    #pragma unroll
    for (int j = 0; j < 4; j++) { f32x4 z = {0.f,0.f,0.f,0.f}; acc[i][j] = z; }

  #pragma unroll
  for (int i = 0; i < 4; i++) { gll16(gA[i], &As[0][dofs[i]]); gll16(gB[i], &Bs[0][dofs[i]]); }
  asm volatile("s_waitcnt vmcnt(0)" ::: "memory");
  __builtin_amdgcn_s_barrier();

  int nsteps = Kdim >> 6;
  int cur = 0;
  for (int ks = 0; ks < nsteps; ks++) {
    if (ks + 1 < nsteps) {
      int k0n = (ks + 1) << 6;
      #pragma unroll
      for (int i = 0; i < 4; i++) {
        gll16(gA[i] + k0n, &As[cur ^ 1][dofs[i]]);
        gll16(gB[i] + k0n, &Bs[cur ^ 1][dofs[i]]);
      }
      asm volatile("s_waitcnt vmcnt(8)" ::: "memory");
    } else {
      asm volatile("s_waitcnt vmcnt(0)" ::: "memory");
    }
    __builtin_amdgcn_s_barrier();
    #pragma unroll
    for (int kk = 0; kk < 2; kk++) {
      short8 af[4], bfv[4];
      #pragma unroll
      for (int i = 0; i < 4; i++) {
        int row = wm * 64 + i * 16 + (lane & 15);
        int ck = (kk * 4 + (lane >> 4)) ^ (row & 7);
        af[i] = *(const short8*)&As[cur][row * 64 + ck * 8];
      }
      #pragma unroll
      for (int j = 0; j < 4; j++) {
        int row = wn * 64 + j * 16 + (lane & 15);
        int ck = (kk * 4 + (lane >> 4)) ^ (row & 7);
        bfv[j] = *(const short8*)&Bs[cur][row * 64 + ck * 8];
      }
      #pragma unroll
      for (int i = 0; i < 4; i++)
        #pragma unroll
        for (int j = 0; j < 4; j++)
          acc[i][j] = __builtin_amdgcn_mfma_f32_16x16x32_bf16(af[i], bfv[j], acc[i][j], 0, 0, 0);
    }
    __builtin_amdgcn_s_barrier();
    cur ^= 1;
  }

  float bj[4]; int colb[4];
  #pragma unroll
  for (int j = 0; j < 4; j++) {
    colb[j] = bcol0 + wn * 64 + j * 16 + (lane & 15);
    bj[j] = bias[colb[j]];
  }
  #pragma unroll
  for (int i = 0; i < 4; i++) {
    #pragma unroll
    for (int r = 0; r < 4; r++) {
      int row = arow0 + wm * 64 + i * 16 + (lane >> 4) * 4 + r;
      #pragma unroll
      for (int j = 0; j < 4; j++)
        Cout[(size_t)row * Ncols + colb[j]] = f2bf(fmaxf(acc[i][j][r] + bj[j], 0.f));
    }
  }
}

// ---------- 32x256 GEMM + residual + LayerNorm, 256 thr; counted vmcnt(9) ----------
// OUTF: write fp32 out; OUTBF: write bf16 out; RESBF: residual is bf16 (else fp32)
template<bool OUTF, bool OUTBF, bool RESBF>
__global__ __launch_bounds__(256) void k_gemm_ln(const ushort_t* __restrict__ A,
    const ushort_t* __restrict__ W, const float* __restrict__ bias,
    const void* __restrict__ R, const float* __restrict__ gamma,
    const float* __restrict__ beta, float* __restrict__ outF,
    ushort_t* __restrict__ outB, int Kdim) {
  __shared__ __align__(16) ushort_t As[2][32 * 64];    // 8KB
  __shared__ __align__(16) ushort_t Bs[2][256 * 64];   // 64KB
  __shared__ float red_s[32 * 4];
  __shared__ float red_q[32 * 4];
  int tid = threadIdx.x;
  int wid = tid >> 6, lane = tid & 63;
  int wn = wid;
  int row0 = blockIdx.x * 32;

  const ushort_t* gA; int dofsA;
  {
    int r = tid >> 3, ck = (tid & 7) ^ (r & 7);
    gA = A + (size_t)(row0 + r) * Kdim + ck * 8;
    dofsA = (wid * 64) * 8;
  }
  const ushort_t* gB[8]; int dofsB[8];
  #pragma unroll
  for (int i = 0; i < 8; i++) {
    int s = i * 256 + tid;
    int r = s >> 3, ck = (s & 7) ^ (r & 7);
    gB[i] = W + (size_t)r * Kdim + ck * 8;
    dofsB[i] = (i * 256 + wid * 64) * 8;
  }

  f32x4 acc[2][4];
  #pragma unroll
  for (int i = 0; i < 2; i++)
    #pragma unroll
    for (int n = 0; n < 4; n++) { f32x4 z = {0.f,0.f,0.f,0.f}; acc[i][n] = z; }

  gll16(gA, &As[0][dofsA]);
  #pragma unroll
  for (int i = 0; i < 8; i++) gll16(gB[i], &Bs[0][dofsB[i]]);
  asm volatile("s_waitcnt vmcnt(0)" ::: "memory");
  __builtin_amdgcn_s_barrier();

  int nsteps = Kdim >> 6;
  int cur = 0;
  for (int ks = 0; ks < nsteps; ks++) {
    if (ks + 1 < nsteps) {
      int k0n = (ks + 1) << 6;
      gll16(gA + k0n, &As[cur ^ 1][dofsA]);
      #pragma unroll
      for (int i = 0; i < 8; i++) gll16(gB[i] + k0n, &Bs[cur ^ 1][dofsB[i]]);
      asm volatile("s_waitcnt vmcnt(9)" ::: "memory");
    } else {
      asm volatile("s_waitcnt vmcnt(0)" ::: "memory");
    }
    __builtin_amdgcn_s_barrier();
    #pragma unroll
    for (int kk = 0; kk < 2; kk++) {
      short8 af[2], bfv[4];
      #pragma unroll
      for (int i = 0; i < 2; i++) {
        int row = i * 16 + (lane & 15);
        int ck = (kk * 4 + (lane >> 4)) ^ (row & 7);
        af[i] = *(const short8*)&As[cur][row * 64 + ck * 8];
      }
      #pragma unroll
      for (int n = 0; n < 4; n++) {
        int row = wn * 64 + n * 16 + (lane & 15);
        int ck = (kk * 4 + (lane >> 4)) ^ (row & 7);
        bfv[n] = *(const short8*)&Bs[cur][row * 64 + ck * 8];
      }
      #pragma unroll
      for (int i = 0; i < 2; i++)
        #pragma unroll
        for (int n = 0; n < 4; n++)
          acc[i][n] = __builtin_amdgcn_mfma_f32_16x16x32_bf16(af[i], bfv[n], acc[i][n], 0, 0, 0);
    }
    __builtin_amdgcn_s_barrier();
    cur ^= 1;
  }

  int col[4]; float bc[4], gm[4], bt[4];
  #pragma unroll
  for (int n = 0; n < 4; n++) {
    col[n] = wn * 64 + n * 16 + (lane & 15);
    bc[n] = bias[col[n]]; gm[n] = gamma[col[n]]; bt[n] = beta[col[n]];
  }
  #pragma unroll
  for (int i = 0; i < 2; i++) {
    #pragma unroll
    for (int r = 0; r < 4; r++) {
      int row_l = i * 16 + (lane >> 4) * 4 + r;
      size_t rbase = (size_t)(row0 + row_l) * HD;
      float s = 0.f, q = 0.f;
      #pragma unroll
      for (int n = 0; n < 4; n++) {
        float rv = RESBF ? bf2f(((const ushort_t*)R)[rbase + col[n]])
                         : ((const float*)R)[rbase + col[n]];
        float v = acc[i][n][r] + bc[n] + rv;
        acc[i][n][r] = v;
        s += v; q += v * v;
      }
      #pragma unroll
      for (int o = 1; o < 16; o <<= 1) { s += __shfl_xor(s, o, 64); q += __shfl_xor(q, o, 64); }
      if ((lane & 15) == 0) { red_s[row_l * 4 + wn] = s; red_q[row_l * 4 + wn] = q; }
    }
  }
  __syncthreads();
  #pragma unroll
  for (int i = 0; i < 2; i++) {
    #pragma unroll
    for (int r = 0; r < 4; r++) {
      int row_l = i * 16 + (lane >> 4) * 4 + r;
      float ssum = red_s[row_l * 4] + red_s[row_l * 4 + 1] + red_s[row_l * 4 + 2] + red_s[row_l * 4 + 3];
      float qsum = red_q[row_l * 4] + red_q[row_l * 4 + 1] + red_q[row_l * 4 + 2] + red_q[row_l * 4 + 3];
      float mu = ssum * (1.f / HD);
      float var = qsum * (1.f / HD) - mu * mu;
      float inv = rsqrtf(var + 1e-5f);
      size_t rb = (size_t)(row0 + row_l) * HD;
      #pragma unroll
      for (int n = 0; n < 4; n++) {
        float v = (acc[i][n][r] - mu) * inv * gm[n] + bt[n];
        if (OUTF) outF[rb + col[n]] = v;
        if (OUTBF) outB[rb + col[n]] = f2bf(v);
      }
    }
  }
}

// ---------- fused masked attention: 512 thr, (b,h,half) blocks, permlane PV ----------
__global__ __launch_bounds__(512) void k_attn(const ushort_t* __restrict__ qkb,
    const u32* __restrict__ adj, const int* __restrict__ offs,
    const float* __restrict__ bqk, ushort_t* __restrict__ attOb) {
  int bid = blockIdx.x;               // b(4b) | h(3b) | half(1b)
  int half = bid & 1, hh = (bid >> 1) & 7, b = bid >> 4;
  int nstart = offs[b], len = offs[b + 1] - nstart;
  int lenT = len >> 5;                // len % 32 == 0

  __shared__ __align__(16) ushort_t K_lds[4 * 512 * 8];    // 32KB [cc][t][8]
  __shared__ __align__(16) ushort_t Kt_lds[64 * 32 * 8];   // 32KB [tchunk][d][8]

  int tid = threadIdx.x;
  {
    const ushort_t* kg = qkb + (size_t)nstart * 512 + 256 + hh * 32;
    for (int t = tid; t < len; t += 512) {
      const uint4* src = (const uint4*)(kg + (size_t)t * 512);
      uint4 v0 = src[0], v1 = src[1], v2 = src[2], v3 = src[3];
      *(uint4*)&K_lds[0 * 4096 + t * 8] = v0;
      *(uint4*)&K_lds[1 * 4096 + t * 8] = v1;
      *(uint4*)&K_lds[2 * 4096 + t * 8] = v2;
      *(uint4*)&K_lds[3 * 4096 + t * 8] = v3;
    }
  }
  __syncthreads();
  {
    int d = tid & 31, tg = tid >> 5;          // tg in [0,16)
    int cc = d >> 3, e = d & 7;
    #pragma unroll
    for (int i = 0; i < 4; i++) {
      int t0 = tg * 32 + i * 8;
      if (t0 < len) {
        u32 w0 = (u32)K_lds[cc * 4096 + (t0 + 0) * 8 + e] | ((u32)K_lds[cc * 4096 + (t0 + 1) * 8 + e] << 16);
        u32 w1 = (u32)K_lds[cc * 4096 + (t0 + 2) * 8 + e] | ((u32)K_lds[cc * 4096 + (t0 + 3) * 8 + e] << 16);
        u32 w2 = (u32)K_lds[cc * 4096 + (t0 + 4) * 8 + e] | ((u32)K_lds[cc * 4096 + (t0 + 5) * 8 + e] << 16);
        u32 w3 = (u32)K_lds[cc * 4096 + (t0 + 6) * 8 + e] | ((u32)K_lds[cc * 4096 + (t0 + 7) * 8 + e] << 16);
        uint4 pk = {w0, w1, w2, w3};
        *(uint4*)&Kt_lds[(t0 >> 3) * 256 + d * 8] = pk;
      }
    }
  }
  __syncthreads();

  int w = tid >> 6, lane = tid & 63;
  int q0w = half * 256 + w * 32;
  if (q0w >= len) return;   // no barriers below (wave-uniform)

  int lq = lane & 31, hf = lane >> 5;
  const float SCALE = 0.17677669529663687f;  // 1/sqrt(32)

  size_t qrow = (size_t)(nstart + q0w + lq) * 512 + hh * 32;
  short8 qf0 = *(const short8*)(qkb + qrow + hf * 8);
  short8 qf1 = *(const short8*)(qkb + qrow + 16 + hf * 8);

  const uint4* ap = (const uint4*)(adj + (size_t)(b * S_MAX + q0w + lq) * ADJW);
  uint4 a0 = ap[0], a1 = ap[1], a2 = ap[2], a3 = ap[3];
  u32 aw[16] = {a0.x, a0.y, a0.z, a0.w, a1.x, a1.y, a1.z, a1.w,
                a2.x, a2.y, a2.z, a2.w, a3.x, a3.y, a3.z, a3.w};

  f32x16 oacc = {0.f,0.f,0.f,0.f,0.f,0.f,0.f,0.f,0.f,0.f,0.f,0.f,0.f,0.f,0.f,0.f};
  float lsum = 0.f;

  for (int tt = 0; tt < lenT; tt++) {
    int t0 = tt * 32;
    short8 ka0 = *(const short8*)&K_lds[hf * 4096 + (t0 + lq) * 8];
    short8 ka1 = *(const short8*)&K_lds[(2 + hf) * 4096 + (t0 + lq) * 8];
    f32x16 sc = {0.f,0.f,0.f,0.f,0.f,0.f,0.f,0.f,0.f,0.f,0.f,0.f,0.f,0.f,0.f,0.f};
    sc = __builtin_amdgcn_mfma_f32_32x32x16_bf16(ka0, qf0, sc, 0, 0, 0);
    sc = __builtin_amdgcn_mfma_f32_32x32x16_bf16(ka1, qf1, sc, 0, 0, 0);
    u32 word = aw[tt];
    float p[16];
    #pragma unroll
    for (int r = 0; r < 16; r++) {
      int tb = (r & 3) + 8 * (r >> 2) + 4 * hf;
      float pe = __expf(sc[r] * SCALE);
      p[r] = ((word >> tb) & 1u) ? 0.f : pe;
      lsum += p[r];
    }
    // pack P^T to bf16 pairs; permlane32_swap builds both B-frag halves at once
    u32 q0 = (u32)f2bf(p[0])  | ((u32)f2bf(p[1])  << 16);
    u32 q1 = (u32)f2bf(p[2])  | ((u32)f2bf(p[3])  << 16);
    u32 q2 = (u32)f2bf(p[4])  | ((u32)f2bf(p[5])  << 16);
    u32 q3 = (u32)f2bf(p[6])  | ((u32)f2bf(p[7])  << 16);
    u32 q4 = (u32)f2bf(p[8])  | ((u32)f2bf(p[9])  << 16);
    u32 q5 = (u32)f2bf(p[10]) | ((u32)f2bf(p[11]) << 16);
    u32 q6 = (u32)f2bf(p[12]) | ((u32)f2bf(p[13]) << 16);
    u32 q7 = (u32)f2bf(p[14]) | ((u32)f2bf(p[15]) << 16);
    asm volatile("v_permlane32_swap_b32 %0, %1" : "+v"(q0), "+v"(q2));
    asm volatile("v_permlane32_swap_b32 %0, %1" : "+v"(q1), "+v"(q3));
    asm volatile("v_permlane32_swap_b32 %0, %1" : "+v"(q4), "+v"(q6));
    asm volatile("v_permlane32_swap_b32 %0, %1" : "+v"(q5), "+v"(q7));
    u32x4 f0v = {q0, q1, q2, q3};
    u32x4 f1v = {q4, q5, q6, q7};
    short8 pb0 = __builtin_bit_cast(short8, f0v);
    short8 pb1 = __builtin_bit_cast(short8, f1v);
    short8 va0 = *(const short8*)&Kt_lds[(t0 / 8 + hf) * 256 + lq * 8];
    short8 va1 = *(const short8*)&Kt_lds[(t0 / 8 + 2 + hf) * 256 + lq * 8];
    oacc = __builtin_amdgcn_mfma_f32_32x32x16_bf16(va0, pb0, oacc, 0, 0, 0);
    oacc = __builtin_amdgcn_mfma_f32_32x32x16_bf16(va1, pb1, oacc, 0, 0, 0);
  }

  const float* bkh = bqk + 256 + hh * 32;
  float pq = 0.f;
  #pragma unroll
  for (int j = 0; j < 8; j++) pq += bf2f((ushort_t)qf0[j]) * bkh[hf * 8 + j];
  #pragma unroll
  for (int j = 0; j < 8; j++) pq += bf2f((ushort_t)qf1[j]) * bkh[16 + hf * 8 + j];
  pq += __shfl_xor(pq, 32, 64);
  float pe_pad = __expf(pq * SCALE) * (float)(S_MAX - len);

  float ltot = lsum + __shfl_xor(lsum, 32, 64) + pe_pad;
  float inv = 1.f / ltot;
  {
    int node = nstart + q0w + lq;
    ushort_t* op = attOb + (size_t)node * HD + hh * DH;
    #pragma unroll
    for (int g = 0; g < 4; g++) {
      float v0 = (oacc[4 * g]     + pe_pad * bkh[g * 8 + hf * 4 + 0]) * inv;
      float v1 = (oacc[4 * g + 1] + pe_pad * bkh[g * 8 + hf * 4 + 1]) * inv;
      float v2 = (oacc[4 * g + 2] + pe_pad * bkh[g * 8 + hf * 4 + 2]) * inv;
      float v3 = (oacc[4 * g + 3] + pe_pad * bkh[g * 8 + hf * 4 + 3]) * inv;
      u32 lo = (u32)f2bf(v0) | ((u32)f2bf(v1) << 16);
      u32 hi = (u32)f2bf(v2) | ((u32)f2bf(v3) << 16);
      uint2 pk = {lo, hi};
      *(uint2*)(op + g * 8 + hf * 4) = pk;
    }
  }
}

extern "C" void kernel_launch(void* const* d_in, const int* in_sizes, int n_in,
                              void* d_out, int out_size, void* d_ws, size_t ws_size,
                              hipStream_t stream) {
  const float* h   = (const float*)d_in[0];
  const float* Wq  = (const float*)d_in[1];
  const float* bq  = (const float*)d_in[2];
  const float* Wk  = (const float*)d_in[3];
  const float* bk  = (const float*)d_in[4];
  // d_in[5], d_in[6] (Wv, bv) unused: reference V uses the K projection
  const float* Wo  = (const float*)d_in[7];
  const float* bo  = (const float*)d_in[8];
  const float* W1  = (const float*)d_in[9];
  const float* b1  = (const float*)d_in[10];
  const float* W2  = (const float*)d_in[11];
  const float* b2  = (const float*)d_in[12];
  const float* g1  = (const float*)d_in[13];
  const float* be1 = (const float*)d_in[14];
  const float* g2  = (const float*)d_in[15];
  const float* be2 = (const float*)d_in[16];
  const int* batch = (const int*)d_in[17];
  const int* ei    = (const int*)d_in[18];
  int N = in_sizes[0] / HD;       // 6400
  int E = in_sizes[18] / 2;       // 102400

  char* ws = (char*)d_ws;
  ushort_t* hb    = (ushort_t*)(ws);                        // 3.2MB [6400,256] bf16 (later attO)
  ushort_t* attOb = hb;
  ushort_t* qkb   = (ushort_t*)(ws + ((size_t)4 << 20));    // 6.4MB [6400,512] bf16
  ushort_t* h1b   = (ushort_t*)(ws + ((size_t)19 << 20));   // 3.2MB bf16 (LN1 out + residual)
  ushort_t* ff1b  = (ushort_t*)(ws + ((size_t)23 << 20));   // 12.8MB
  char* wbase = ws + ((size_t)36 << 20);
  ushort_t* Wqkb = (ushort_t*)(wbase);                      // 256KB [512,256]
  ushort_t* Wob  = (ushort_t*)(wbase + (256 << 10));        // 128KB
  ushort_t* W1b  = (ushort_t*)(wbase + (384 << 10));        // 512KB [1024,256]
  ushort_t* W2b  = (ushort_t*)(wbase + (896 << 10));        // 512KB [256,1024]
  float*    bqk  = (float*)(wbase + (1408 << 10));          // 2KB  [512]
  u32*      adj  = (u32*)(wbase + (1536 << 10));            // 512KB
  int*      offs = (int*)(ws + ((size_t)38 << 20));         // 128B

  // P1: adj zero | offsets+bias | weight cvt | compact h cvt
  k_prep2<<<1281, 256, 0, stream>>>(adj, batch, N, offs, bq, bk, bqk,
                                    Wq, Wk, Wo, W1, W2,
                                    Wqkb, Wqkb + 65536, Wob, W1b, W2b, h, hb);
  // P2: fused Q|K projection + edge atomics
  k_qk<<<dim3(100, 4), 256, 0, stream>>>(hb, Wqkb, bqk, qkb, 100,
                                         ei, E, batch, offs, adj);
  // P3: attention (512 thr, permlane PV) -> attOb
  k_attn<<<B_G * NH * 2, 512, 0, stream>>>(qkb, adj, offs, bqk, attOb);
  // P4: out-proj + residual(h fp32) + LN1 -> h1b (bf16 only)
  k_gemm_ln<false, true, false><<<200, 256, 0, stream>>>(attOb, Wob, bo, h, g1, be1,
                                                         nullptr, h1b, HD);
  // P5: FFN up + relu (128x128 tile, acc[4][4])
  k_ffup<<<dim3(50, 8), 256, 0, stream>>>(h1b, W1b, b1, ff1b, FFD, HD);
  // P6: FFN down + residual(h1b bf16) + LN2 -> d_out (fp32)
  k_gemm_ln<true, false, true><<<200, 256, 0, stream>>>(ff1b, W2b, b2, h1b, g2, be2,
                                                        (float*)d_out, nullptr, FFD);
}

// Round 16
// 81.391 us; speedup vs baseline: 1.1671x; 1.0363x over previous
//
#include <hip/hip_runtime.h>
#include <math.h>

typedef unsigned int u32;
typedef unsigned short ushort_t;
typedef __attribute__((ext_vector_type(8))) short short8;
typedef __attribute__((ext_vector_type(4))) float f32x4;
typedef __attribute__((ext_vector_type(16))) float f32x16;
typedef __attribute__((ext_vector_type(4))) unsigned int u32x4;

#define B_G 16
#define S_MAX 512
#define NH 8
#define DH 32
#define HD 256
#define FFD 1024
#define ADJW 16            // u32 words per adjacency row (512 bits)

__device__ __forceinline__ ushort_t f2bf(float f) {
  u32 u = __float_as_uint(f);
  u += 0x7fffu + ((u >> 16) & 1u);
  return (ushort_t)(u >> 16);
}
__device__ __forceinline__ float bf2f(ushort_t s) {
  return __uint_as_float(((u32)s) << 16);
}

__device__ __forceinline__ void gll16(const void* g, void* l) {
  __builtin_amdgcn_global_load_lds(
      (const __attribute__((address_space(1))) unsigned int*)g,
      (__attribute__((address_space(3))) unsigned int*)l, 16, 0, 0);
}

// ---------- prep: zero adj | offsets+bias | weight cvt | h cvt (compact) ----------
__global__ __launch_bounds__(256) void k_prep2(u32* __restrict__ adj,
    const int* __restrict__ batch, int N, int* __restrict__ offs,
    const float* __restrict__ bq, const float* __restrict__ bk, float* __restrict__ bqk,
    const float* __restrict__ wa, const float* __restrict__ wb, const float* __restrict__ wc,
    const float* __restrict__ wd, const float* __restrict__ we,
    ushort_t* __restrict__ oa, ushort_t* __restrict__ ob, ushort_t* __restrict__ oc,
    ushort_t* __restrict__ od, ushort_t* __restrict__ oe,
    const float* __restrict__ h, ushort_t* __restrict__ hb) {
  int blk = blockIdx.x, tid = threadIdx.x;
  if (blk < 128) {
    uint4 z = {0u, 0u, 0u, 0u};
    ((uint4*)adj)[blk * 256 + tid] = z;
  } else if (blk == 128) {
    bqk[tid] = bq[tid];
    bqk[HD + tid] = bk[tid];
    if (tid <= B_G) {
      if (tid == B_G) { offs[B_G] = N; }
      else {
        int lo = 0, hi = N;
        while (lo < hi) { int mid = (lo + hi) >> 1; if (batch[mid] < tid) lo = mid + 1; else hi = mid; }
        offs[tid] = lo;
      }
    }
  } else if (blk < 481) {
    int bb = blk - 129;
    const float* src; ushort_t* dst; int off;
    if (bb < 32)       { src = wa; dst = oa; off = bb; }
    else if (bb < 64)  { src = wb; dst = ob; off = bb - 32; }
    else if (bb < 96)  { src = wc; dst = oc; off = bb - 64; }
    else if (bb < 224) { src = wd; dst = od; off = bb - 96; }
    else               { src = we; dst = oe; off = bb - 224; }
    size_t i = (size_t)off * 2048 + tid * 8;
    float4 v0 = *(const float4*)&src[i];
    float4 v1 = *(const float4*)&src[i + 4];
    uint4 pk;
    pk.x = (u32)f2bf(v0.x) | ((u32)f2bf(v0.y) << 16);
    pk.y = (u32)f2bf(v0.z) | ((u32)f2bf(v0.w) << 16);
    pk.z = (u32)f2bf(v1.x) | ((u32)f2bf(v1.y) << 16);
    pk.w = (u32)f2bf(v1.z) | ((u32)f2bf(v1.w) << 16);
    *(uint4*)&dst[i] = pk;
  } else {
    size_t i = ((size_t)(blk - 481) * 256 + tid) * 8;
    float4 v0 = *(const float4*)&h[i];
    float4 v1 = *(const float4*)&h[i + 4];
    uint4 pk;
    pk.x = (u32)f2bf(v0.x) | ((u32)f2bf(v0.y) << 16);
    pk.y = (u32)f2bf(v0.z) | ((u32)f2bf(v0.w) << 16);
    pk.z = (u32)f2bf(v1.x) | ((u32)f2bf(v1.y) << 16);
    pk.w = (u32)f2bf(v1.z) | ((u32)f2bf(v1.w) << 16);
    *(uint4*)&hb[i] = pk;
  }
}

// ---------- QK GEMM: 64x128 tile, BK=64, 256 thr; counted-vmcnt pipeline ----------
__global__ __launch_bounds__(256) void k_qk(const ushort_t* __restrict__ A,
    const ushort_t* __restrict__ W, const float* __restrict__ bias,
    ushort_t* __restrict__ Cout, int gridx,
    const int* __restrict__ ei, int E, const int* __restrict__ batch,
    const int* __restrict__ offs, u32* __restrict__ adj) {
  __shared__ __align__(16) ushort_t As[2][64 * 64];
  __shared__ __align__(16) ushort_t Bs[2][128 * 64];
  int tid = threadIdx.x;
  int wid = tid >> 6, lane = tid & 63;
  int wm = wid & 1, wn = wid >> 1;
  int arow0 = blockIdx.x * 64, bcol0 = blockIdx.y * 128;

  {
    int e = (blockIdx.y * gridx + blockIdx.x) * 256 + tid;
    if (e < E) {
      int s = ei[e], d = ei[E + e];
      int b = batch[s];
      int o = offs[b];
      atomicOr(&adj[(b * S_MAX + (s - o)) * ADJW + ((d - o) >> 5)], 1u << ((d - o) & 31));
    }
  }

  const ushort_t* gA[2]; const ushort_t* gB[4];
  int dofsA[2], dofsB[4];
  #pragma unroll
  for (int i = 0; i < 2; i++) {
    int s = i * 256 + wid * 64 + lane;
    int r = s >> 3, ck = (s & 7) ^ (r & 7);
    gA[i] = A + (size_t)(arow0 + r) * HD + ck * 8;
    dofsA[i] = (i * 256 + wid * 64) * 8;
  }
  #pragma unroll
  for (int i = 0; i < 4; i++) {
    int s = i * 256 + wid * 64 + lane;
    int r = s >> 3, ck = (s & 7) ^ (r & 7);
    gB[i] = W + (size_t)(bcol0 + r) * HD + ck * 8;
    dofsB[i] = (i * 256 + wid * 64) * 8;
  }

  f32x4 acc[2][4];
  #pragma unroll
  for (int i = 0; i < 2; i++)
    #pragma unroll
    for (int j = 0; j < 4; j++) { f32x4 z = {0.f,0.f,0.f,0.f}; acc[i][j] = z; }

  #pragma unroll
  for (int i = 0; i < 2; i++) gll16(gA[i], &As[0][dofsA[i]]);
  #pragma unroll
  for (int i = 0; i < 4; i++) gll16(gB[i], &Bs[0][dofsB[i]]);
  asm volatile("s_waitcnt vmcnt(0)" ::: "memory");
  __builtin_amdgcn_s_barrier();

  int cur = 0;
  for (int ks = 0; ks < 4; ks++) {
    if (ks < 3) {
      int k0n = (ks + 1) << 6;
      #pragma unroll
      for (int i = 0; i < 2; i++) gll16(gA[i] + k0n, &As[cur ^ 1][dofsA[i]]);
      #pragma unroll
      for (int i = 0; i < 4; i++) gll16(gB[i] + k0n, &Bs[cur ^ 1][dofsB[i]]);
      asm volatile("s_waitcnt vmcnt(6)" ::: "memory");
    } else {
      asm volatile("s_waitcnt vmcnt(0)" ::: "memory");
    }
    __builtin_amdgcn_s_barrier();
    #pragma unroll
    for (int kk = 0; kk < 2; kk++) {
      short8 af[2], bfv[4];
      #pragma unroll
      for (int i = 0; i < 2; i++) {
        int row = wm * 32 + i * 16 + (lane & 15);
        int ck = (kk * 4 + (lane >> 4)) ^ (row & 7);
        af[i] = *(const short8*)&As[cur][row * 64 + ck * 8];
      }
      #pragma unroll
      for (int j = 0; j < 4; j++) {
        int row = wn * 64 + j * 16 + (lane & 15);
        int ck = (kk * 4 + (lane >> 4)) ^ (row & 7);
        bfv[j] = *(const short8*)&Bs[cur][row * 64 + ck * 8];
      }
      #pragma unroll
      for (int i = 0; i < 2; i++)
        #pragma unroll
        for (int j = 0; j < 4; j++)
          acc[i][j] = __builtin_amdgcn_mfma_f32_16x16x32_bf16(af[i], bfv[j], acc[i][j], 0, 0, 0);
    }
    __builtin_amdgcn_s_barrier();
    cur ^= 1;
  }

  float bj[4]; int colb[4];
  #pragma unroll
  for (int j = 0; j < 4; j++) {
    colb[j] = bcol0 + wn * 64 + j * 16 + (lane & 15);
    bj[j] = bias[colb[j]];
  }
  #pragma unroll
  for (int i = 0; i < 2; i++) {
    #pragma unroll
    for (int r = 0; r < 4; r++) {
      int row = arow0 + wm * 32 + i * 16 + (lane >> 4) * 4 + r;
      #pragma unroll
      for (int j = 0; j < 4; j++)
        Cout[(size_t)row * 512 + colb[j]] = f2bf(acc[i][j][r] + bj[j]);
    }
  }
}

// ---------- FFN-up GEMM: 128x128 tile, 4 waves (2x2), acc[4][4], BK=64 ----------
__global__ __launch_bounds__(256) void k_ffup(const ushort_t* __restrict__ A,
    const ushort_t* __restrict__ W, const float* __restrict__ bias,
    ushort_t* __restrict__ Cout, int Ncols, int Kdim) {
  __shared__ __align__(16) ushort_t As[2][128 * 64];   // 32KB
  __shared__ __align__(16) ushort_t Bs[2][128 * 64];   // 32KB
  int tid = threadIdx.x;
  int wid = tid >> 6, lane = tid & 63;
  int wm = wid & 1, wn = wid >> 1;
  int arow0 = blockIdx.x * 128, bcol0 = blockIdx.y * 128;

  const ushort_t* gA[4]; const ushort_t* gB[4];
  int dofs[4];
  #pragma unroll
  for (int i = 0; i < 4; i++) {
    int s = i * 256 + tid;
    int r = s >> 3, ck = (s & 7) ^ (r & 7);
    gA[i] = A + (size_t)(arow0 + r) * Kdim + ck * 8;
    gB[i] = W + (size_t)(bcol0 + r) * Kdim + ck * 8;
    dofs[i] = (i * 256 + wid * 64) * 8;
  }

  f32x4 acc[4][4];
  #pragma unroll
  for (int i = 0; i < 4; i++)
    #pragma unroll
    for (int j = 0; j < 4; j++) { f32x4 z = {0.f,0.f,0.f,0.f}; acc[i][j] = z; }

  #pragma unroll
  for (int i = 0; i < 4; i++) { gll16(gA[i], &As[0][dofs[i]]); gll16(gB[i], &Bs[0][dofs[i]]); }
  asm volatile("s_waitcnt vmcnt(0)" ::: "memory");
  __builtin_amdgcn_s_barrier();

  int nsteps = Kdim >> 6;
  int cur = 0;
  for (int ks = 0; ks < nsteps; ks++) {
    if (ks + 1 < nsteps) {
      int k0n = (ks + 1) << 6;
      #pragma unroll
      for (int i = 0; i < 4; i++) {
        gll16(gA[i] + k0n, &As[cur ^ 1][dofs[i]]);
        gll16(gB[i] + k0n, &Bs[cur ^ 1][dofs[i]]);
      }
      asm volatile("s_waitcnt vmcnt(8)" ::: "memory");
    } else {
      asm volatile("s_waitcnt vmcnt(0)" ::: "memory");
    }
    __builtin_amdgcn_s_barrier();
    #pragma unroll
    for (int kk = 0; kk < 2; kk++) {
      short8 af[4], bfv[4];
      #pragma unroll
      for (int i = 0; i < 4; i++) {
        int row = wm * 64 + i * 16 + (lane & 15);
        int ck = (kk * 4 + (lane >> 4)) ^ (row & 7);
        af[i] = *(const short8*)&As[cur][row * 64 + ck * 8];
      }
      #pragma unroll
      for (int j = 0; j < 4; j++) {
        int row = wn * 64 + j * 16 + (lane & 15);
        int ck = (kk * 4 + (lane >> 4)) ^ (row & 7);
        bfv[j] = *(const short8*)&Bs[cur][row * 64 + ck * 8];
      }
      #pragma unroll
      for (int i = 0; i < 4; i++)
        #pragma unroll
        for (int j = 0; j < 4; j++)
          acc[i][j] = __builtin_amdgcn_mfma_f32_16x16x32_bf16(af[i], bfv[j], acc[i][j], 0, 0, 0);
    }
    __builtin_amdgcn_s_barrier();
    cur ^= 1;
  }

  float bj[4]; int colb[4];
  #pragma unroll
  for (int j = 0; j < 4; j++) {
    colb[j] = bcol0 + wn * 64 + j * 16 + (lane & 15);
    bj[j] = bias[colb[j]];
  }
  #pragma unroll
  for (int i = 0; i < 4; i++) {
    #pragma unroll
    for (int r = 0; r < 4; r++) {
      int row = arow0 + wm * 64 + i * 16 + (lane >> 4) * 4 + r;
      #pragma unroll
      for (int j = 0; j < 4; j++)
        Cout[(size_t)row * Ncols + colb[j]] = f2bf(fmaxf(acc[i][j][r] + bj[j], 0.f));
    }
  }
}

// ---------- MRx256 GEMM + residual + LayerNorm, 256 thr; counted vmcnt(9) ----------
// R16: 16-row tiles (grid 400 > 256 CUs -> 2 blocks/CU TLP; A staged by lanes
// 0-31 of each wave, masked gll16 still counts 1 vmem/wave so vmcnt math holds).
// else: 32-row tiles (grid 200).
template<bool OUTF, bool OUTBF, bool RESBF, bool R16>
__global__ __launch_bounds__(256) void k_gemm_ln(const ushort_t* __restrict__ A,
    const ushort_t* __restrict__ W, const float* __restrict__ bias,
    const void* __restrict__ R, const float* __restrict__ gamma,
    const float* __restrict__ beta, float* __restrict__ outF,
    ushort_t* __restrict__ outB, int Kdim) {
  constexpr int MR = R16 ? 16 : 32;
  constexpr int MI = R16 ? 1 : 2;
  __shared__ __align__(16) ushort_t As[2][MR * 64];
  __shared__ __align__(16) ushort_t Bs[2][256 * 64];   // 64KB
  __shared__ float red_s[MR * 4];
  __shared__ float red_q[MR * 4];
  int tid = threadIdx.x;
  int wid = tid >> 6, lane = tid & 63;
  int wn = wid;
  int row0 = blockIdx.x * MR;

  const ushort_t* gA; int dofsA; bool doA;
  if (R16) {
    int s = wid * 32 + (lane & 31);
    int r = s >> 3, ck = (s & 7) ^ (r & 7);
    gA = A + (size_t)(row0 + r) * Kdim + ck * 8;
    dofsA = (wid * 32) * 8;          // wave-uniform LDS base; HW adds lane*16B
    doA = (lane < 32);
  } else {
    int r = tid >> 3, ck = (tid & 7) ^ (r & 7);
    gA = A + (size_t)(row0 + r) * Kdim + ck * 8;
    dofsA = (wid * 64) * 8;
    doA = true;
  }
  const ushort_t* gB[8]; int dofsB[8];
  #pragma unroll
  for (int i = 0; i < 8; i++) {
    int s = i * 256 + tid;
    int r = s >> 3, ck = (s & 7) ^ (r & 7);
    gB[i] = W + (size_t)r * Kdim + ck * 8;
    dofsB[i] = (i * 256 + wid * 64) * 8;
  }

  f32x4 acc[MI][4];
  #pragma unroll
  for (int i = 0; i < MI; i++)
    #pragma unroll
    for (int n = 0; n < 4; n++) { f32x4 z = {0.f,0.f,0.f,0.f}; acc[i][n] = z; }

  if (doA) gll16(gA, &As[0][dofsA]);
  #pragma unroll
  for (int i = 0; i < 8; i++) gll16(gB[i], &Bs[0][dofsB[i]]);
  asm volatile("s_waitcnt vmcnt(0)" ::: "memory");
  __builtin_amdgcn_s_barrier();

  int nsteps = Kdim >> 6;
  int cur = 0;
  for (int ks = 0; ks < nsteps; ks++) {
    if (ks + 1 < nsteps) {
      int k0n = (ks + 1) << 6;
      if (doA) gll16(gA + k0n, &As[cur ^ 1][dofsA]);
      #pragma unroll
      for (int i = 0; i < 8; i++) gll16(gB[i] + k0n, &Bs[cur ^ 1][dofsB[i]]);
      asm volatile("s_waitcnt vmcnt(9)" ::: "memory");
    } else {
      asm volatile("s_waitcnt vmcnt(0)" ::: "memory");
    }
    __builtin_amdgcn_s_barrier();
    #pragma unroll
    for (int kk = 0; kk < 2; kk++) {
      short8 af[MI], bfv[4];
      #pragma unroll
      for (int i = 0; i < MI; i++) {
        int row = i * 16 + (lane & 15);
        int ck = (kk * 4 + (lane >> 4)) ^ (row & 7);
        af[i] = *(const short8*)&As[cur][row * 64 + ck * 8];
      }
      #pragma unroll
      for (int n = 0; n < 4; n++) {
        int row = wn * 64 + n * 16 + (lane & 15);
        int ck = (kk * 4 + (lane >> 4)) ^ (row & 7);
        bfv[n] = *(const short8*)&Bs[cur][row * 64 + ck * 8];
      }
      #pragma unroll
      for (int i = 0; i < MI; i++)
        #pragma unroll
        for (int n = 0; n < 4; n++)
          acc[i][n] = __builtin_amdgcn_mfma_f32_16x16x32_bf16(af[i], bfv[n], acc[i][n], 0, 0, 0);
    }
    __builtin_amdgcn_s_barrier();
    cur ^= 1;
  }

  int col[4]; float bc[4], gm[4], bt[4];
  #pragma unroll
  for (int n = 0; n < 4; n++) {
    col[n] = wn * 64 + n * 16 + (lane & 15);
    bc[n] = bias[col[n]]; gm[n] = gamma[col[n]]; bt[n] = beta[col[n]];
  }
  #pragma unroll
  for (int i = 0; i < MI; i++) {
    #pragma unroll
    for (int r = 0; r < 4; r++) {
      int row_l = i * 16 + (lane >> 4) * 4 + r;
      size_t rbase = (size_t)(row0 + row_l) * HD;
      float s = 0.f, q = 0.f;
      #pragma unroll
      for (int n = 0; n < 4; n++) {
        float rv = RESBF ? bf2f(((const ushort_t*)R)[rbase + col[n]])
                         : ((const float*)R)[rbase + col[n]];
        float v = acc[i][n][r] + bc[n] + rv;
        acc[i][n][r] = v;
        s += v; q += v * v;
      }
      #pragma unroll
      for (int o = 1; o < 16; o <<= 1) { s += __shfl_xor(s, o, 64); q += __shfl_xor(q, o, 64); }
      if ((lane & 15) == 0) { red_s[row_l * 4 + wn] = s; red_q[row_l * 4 + wn] = q; }
    }
  }
  __syncthreads();
  #pragma unroll
  for (int i = 0; i < MI; i++) {
    #pragma unroll
    for (int r = 0; r < 4; r++) {
      int row_l = i * 16 + (lane >> 4) * 4 + r;
      float ssum = red_s[row_l * 4] + red_s[row_l * 4 + 1] + red_s[row_l * 4 + 2] + red_s[row_l * 4 + 3];
      float qsum = red_q[row_l * 4] + red_q[row_l * 4 + 1] + red_q[row_l * 4 + 2] + red_q[row_l * 4 + 3];
      float mu = ssum * (1.f / HD);
      float var = qsum * (1.f / HD) - mu * mu;
      float inv = rsqrtf(var + 1e-5f);
      size_t rb = (size_t)(row0 + row_l) * HD;
      #pragma unroll
      for (int n = 0; n < 4; n++) {
        float v = (acc[i][n][r] - mu) * inv * gm[n] + bt[n];
        if (OUTF) outF[rb + col[n]] = v;
        if (OUTBF) outB[rb + col[n]] = f2bf(v);
      }
    }
  }
}

// ---------- fused masked attention: 512 thr, (b,h,half) blocks, permlane PV ----------
__global__ __launch_bounds__(512) void k_attn(const ushort_t* __restrict__ qkb,
    const u32* __restrict__ adj, const int* __restrict__ offs,
    const float* __restrict__ bqk, ushort_t* __restrict__ attOb) {
  int bid = blockIdx.x;               // b(4b) | h(3b) | half(1b)
  int half = bid & 1, hh = (bid >> 1) & 7, b = bid >> 4;
  int nstart = offs[b], len = offs[b + 1] - nstart;
  int lenT = len >> 5;                // len % 32 == 0

  __shared__ __align__(16) ushort_t K_lds[4 * 512 * 8];    // 32KB [cc][t][8]
  __shared__ __align__(16) ushort_t Kt_lds[64 * 32 * 8];   // 32KB [tchunk][d][8]

  int tid = threadIdx.x;
  {
    const ushort_t* kg = qkb + (size_t)nstart * 512 + 256 + hh * 32;
    for (int t = tid; t < len; t += 512) {
      const uint4* src = (const uint4*)(kg + (size_t)t * 512);
      uint4 v0 = src[0], v1 = src[1], v2 = src[2], v3 = src[3];
      *(uint4*)&K_lds[0 * 4096 + t * 8] = v0;
      *(uint4*)&K_lds[1 * 4096 + t * 8] = v1;
      *(uint4*)&K_lds[2 * 4096 + t * 8] = v2;
      *(uint4*)&K_lds[3 * 4096 + t * 8] = v3;
    }
  }
  __syncthreads();
  {
    int d = tid & 31, tg = tid >> 5;          // tg in [0,16)
    int cc = d >> 3, e = d & 7;
    #pragma unroll
    for (int i = 0; i < 4; i++) {
      int t0 = tg * 32 + i * 8;
      if (t0 < len) {
        u32 w0 = (u32)K_lds[cc * 4096 + (t0 + 0) * 8 + e] | ((u32)K_lds[cc * 4096 + (t0 + 1) * 8 + e] << 16);
        u32 w1 = (u32)K_lds[cc * 4096 + (t0 + 2) * 8 + e] | ((u32)K_lds[cc * 4096 + (t0 + 3) * 8 + e] << 16);
        u32 w2 = (u32)K_lds[cc * 4096 + (t0 + 4) * 8 + e] | ((u32)K_lds[cc * 4096 + (t0 + 5) * 8 + e] << 16);
        u32 w3 = (u32)K_lds[cc * 4096 + (t0 + 6) * 8 + e] | ((u32)K_lds[cc * 4096 + (t0 + 7) * 8 + e] << 16);
        uint4 pk = {w0, w1, w2, w3};
        *(uint4*)&Kt_lds[(t0 >> 3) * 256 + d * 8] = pk;
      }
    }
  }
  __syncthreads();

  int w = tid >> 6, lane = tid & 63;
  int q0w = half * 256 + w * 32;
  if (q0w >= len) return;   // no barriers below (wave-uniform)

  int lq = lane & 31, hf = lane >> 5;
  const float SCALE = 0.17677669529663687f;  // 1/sqrt(32)

  size_t qrow = (size_t)(nstart + q0w + lq) * 512 + hh * 32;
  short8 qf0 = *(const short8*)(qkb + qrow + hf * 8);
  short8 qf1 = *(const short8*)(qkb + qrow + 16 + hf * 8);

  const uint4* ap = (const uint4*)(adj + (size_t)(b * S_MAX + q0w + lq) * ADJW);
  uint4 a0 = ap[0], a1 = ap[1], a2 = ap[2], a3 = ap[3];
  u32 aw[16] = {a0.x, a0.y, a0.z, a0.w, a1.x, a1.y, a1.z, a1.w,
                a2.x, a2.y, a2.z, a2.w, a3.x, a3.y, a3.z, a3.w};

  f32x16 oacc = {0.f,0.f,0.f,0.f,0.f,0.f,0.f,0.f,0.f,0.f,0.f,0.f,0.f,0.f,0.f,0.f};
  float lsum = 0.f;

  for (int tt = 0; tt < lenT; tt++) {
    int t0 = tt * 32;
    short8 ka0 = *(const short8*)&K_lds[hf * 4096 + (t0 + lq) * 8];
    short8 ka1 = *(const short8*)&K_lds[(2 + hf) * 4096 + (t0 + lq) * 8];
    f32x16 sc = {0.f,0.f,0.f,0.f,0.f,0.f,0.f,0.f,0.f,0.f,0.f,0.f,0.f,0.f,0.f,0.f};
    sc = __builtin_amdgcn_mfma_f32_32x32x16_bf16(ka0, qf0, sc, 0, 0, 0);
    sc = __builtin_amdgcn_mfma_f32_32x32x16_bf16(ka1, qf1, sc, 0, 0, 0);
    u32 word = aw[tt];
    float p[16];
    #pragma unroll
    for (int r = 0; r < 16; r++) {
      int tb = (r & 3) + 8 * (r >> 2) + 4 * hf;
      float pe = __expf(sc[r] * SCALE);
      p[r] = ((word >> tb) & 1u) ? 0.f : pe;
      lsum += p[r];
    }
    // pack P^T to bf16 pairs; permlane32_swap builds both B-frag halves at once
    u32 q0 = (u32)f2bf(p[0])  | ((u32)f2bf(p[1])  << 16);
    u32 q1 = (u32)f2bf(p[2])  | ((u32)f2bf(p[3])  << 16);
    u32 q2 = (u32)f2bf(p[4])  | ((u32)f2bf(p[5])  << 16);
    u32 q3 = (u32)f2bf(p[6])  | ((u32)f2bf(p[7])  << 16);
    u32 q4 = (u32)f2bf(p[8])  | ((u32)f2bf(p[9])  << 16);
    u32 q5 = (u32)f2bf(p[10]) | ((u32)f2bf(p[11]) << 16);
    u32 q6 = (u32)f2bf(p[12]) | ((u32)f2bf(p[13]) << 16);
    u32 q7 = (u32)f2bf(p[14]) | ((u32)f2bf(p[15]) << 16);
    asm volatile("v_permlane32_swap_b32 %0, %1" : "+v"(q0), "+v"(q2));
    asm volatile("v_permlane32_swap_b32 %0, %1" : "+v"(q1), "+v"(q3));
    asm volatile("v_permlane32_swap_b32 %0, %1" : "+v"(q4), "+v"(q6));
    asm volatile("v_permlane32_swap_b32 %0, %1" : "+v"(q5), "+v"(q7));
    u32x4 f0v = {q0, q1, q2, q3};
    u32x4 f1v = {q4, q5, q6, q7};
    short8 pb0 = __builtin_bit_cast(short8, f0v);
    short8 pb1 = __builtin_bit_cast(short8, f1v);
    short8 va0 = *(const short8*)&Kt_lds[(t0 / 8 + hf) * 256 + lq * 8];
    short8 va1 = *(const short8*)&Kt_lds[(t0 / 8 + 2 + hf) * 256 + lq * 8];
    oacc = __builtin_amdgcn_mfma_f32_32x32x16_bf16(va0, pb0, oacc, 0, 0, 0);
    oacc = __builtin_amdgcn_mfma_f32_32x32x16_bf16(va1, pb1, oacc, 0, 0, 0);
  }

  const float* bkh = bqk + 256 + hh * 32;
  float pq = 0.f;
  #pragma unroll
  for (int j = 0; j < 8; j++) pq += bf2f((ushort_t)qf0[j]) * bkh[hf * 8 + j];
  #pragma unroll
  for (int j = 0; j < 8; j++) pq += bf2f((ushort_t)qf1[j]) * bkh[16 + hf * 8 + j];
  pq += __shfl_xor(pq, 32, 64);
  float pe_pad = __expf(pq * SCALE) * (float)(S_MAX - len);

  float ltot = lsum + __shfl_xor(lsum, 32, 64) + pe_pad;
  float inv = 1.f / ltot;
  {
    int node = nstart + q0w + lq;
    ushort_t* op = attOb + (size_t)node * HD + hh * DH;
    #pragma unroll
    for (int g = 0; g < 4; g++) {
      float v0 = (oacc[4 * g]     + pe_pad * bkh[g * 8 + hf * 4 + 0]) * inv;
      float v1 = (oacc[4 * g + 1] + pe_pad * bkh[g * 8 + hf * 4 + 1]) * inv;
      float v2 = (oacc[4 * g + 2] + pe_pad * bkh[g * 8 + hf * 4 + 2]) * inv;
      float v3 = (oacc[4 * g + 3] + pe_pad * bkh[g * 8 + hf * 4 + 3]) * inv;
      u32 lo = (u32)f2bf(v0) | ((u32)f2bf(v1) << 16);
      u32 hi = (u32)f2bf(v2) | ((u32)f2bf(v3) << 16);
      uint2 pk = {lo, hi};
      *(uint2*)(op + g * 8 + hf * 4) = pk;
    }
  }
}

extern "C" void kernel_launch(void* const* d_in, const int* in_sizes, int n_in,
                              void* d_out, int out_size, void* d_ws, size_t ws_size,
                              hipStream_t stream) {
  const float* h   = (const float*)d_in[0];
  const float* Wq  = (const float*)d_in[1];
  const float* bq  = (const float*)d_in[2];
  const float* Wk  = (const float*)d_in[3];
  const float* bk  = (const float*)d_in[4];
  // d_in[5], d_in[6] (Wv, bv) unused: reference V uses the K projection
  const float* Wo  = (const float*)d_in[7];
  const float* bo  = (const float*)d_in[8];
  const float* W1  = (const float*)d_in[9];
  const float* b1  = (const float*)d_in[10];
  const float* W2  = (const float*)d_in[11];
  const float* b2  = (const float*)d_in[12];
  const float* g1  = (const float*)d_in[13];
  const float* be1 = (const float*)d_in[14];
  const float* g2  = (const float*)d_in[15];
  const float* be2 = (const float*)d_in[16];
  const int* batch = (const int*)d_in[17];
  const int* ei    = (const int*)d_in[18];
  int N = in_sizes[0] / HD;       // 6400
  int E = in_sizes[18] / 2;       // 102400

  char* ws = (char*)d_ws;
  ushort_t* hb    = (ushort_t*)(ws);                        // 3.2MB [6400,256] bf16 (later attO)
  ushort_t* attOb = hb;
  ushort_t* qkb   = (ushort_t*)(ws + ((size_t)4 << 20));    // 6.4MB [6400,512] bf16
  ushort_t* h1b   = (ushort_t*)(ws + ((size_t)19 << 20));   // 3.2MB bf16 (LN1 out + residual)
  ushort_t* ff1b  = (ushort_t*)(ws + ((size_t)23 << 20));   // 12.8MB
  char* wbase = ws + ((size_t)36 << 20);
  ushort_t* Wqkb = (ushort_t*)(wbase);                      // 256KB [512,256]
  ushort_t* Wob  = (ushort_t*)(wbase + (256 << 10));        // 128KB
  ushort_t* W1b  = (ushort_t*)(wbase + (384 << 10));        // 512KB [1024,256]
  ushort_t* W2b  = (ushort_t*)(wbase + (896 << 10));        // 512KB [256,1024]
  float*    bqk  = (float*)(wbase + (1408 << 10));          // 2KB  [512]
  u32*      adj  = (u32*)(wbase + (1536 << 10));            // 512KB
  int*      offs = (int*)(ws + ((size_t)38 << 20));         // 128B

  // P1: adj zero | offsets+bias | weight cvt | compact h cvt
  k_prep2<<<1281, 256, 0, stream>>>(adj, batch, N, offs, bq, bk, bqk,
                                    Wq, Wk, Wo, W1, W2,
                                    Wqkb, Wqkb + 65536, Wob, W1b, W2b, h, hb);
  // P2: fused Q|K projection + edge atomics
  k_qk<<<dim3(100, 4), 256, 0, stream>>>(hb, Wqkb, bqk, qkb, 100,
                                         ei, E, batch, offs, adj);
  // P3: attention (512 thr, permlane PV) -> attOb
  k_attn<<<B_G * NH * 2, 512, 0, stream>>>(qkb, adj, offs, bqk, attOb);
  // P4: out-proj + residual(h fp32) + LN1 -> h1b; 16-row tiles, grid 400 (TLP)
  k_gemm_ln<false, true, false, true><<<400, 256, 0, stream>>>(attOb, Wob, bo, h, g1, be1,
                                                               nullptr, h1b, HD);
  // P5: FFN up + relu (128x128 tile, acc[4][4])
  k_ffup<<<dim3(50, 8), 256, 0, stream>>>(h1b, W1b, b1, ff1b, FFD, HD);
  // P6: FFN down + residual(h1b bf16) + LN2 -> d_out; 32-row tiles (W2 reuse)
  k_gemm_ln<true, false, true, false><<<200, 256, 0, stream>>>(ff1b, W2b, b2, h1b, g2, be2,
                                                               (float*)d_out, nullptr, FFD);
}